// Round 1
// baseline (1340.931 us; speedup 1.0000x reference)
//
#include <hip/hip_runtime.h>

#define NTASK 24
#define KSEL 1000
#define NIMG 8
#define NEG_INF_D (-1e30)

// ---------- helpers ----------

// monotone map: float -> u32 preserving numeric order
static __device__ __forceinline__ unsigned fkey(float x) {
    unsigned u = __float_as_uint(x);
    return u ^ ((u >> 31) ? 0xFFFFFFFFu : 0x80000000u);
}

// monotone map: double -> u64 preserving numeric order
static __device__ __forceinline__ unsigned long long dkey(double d) {
    unsigned long long u = (unsigned long long)__double_as_longlong(d);
    if (u >> 63) u = ~u; else u |= 0x8000000000000000ull;
    return u;
}

static __device__ __forceinline__ int level_hw(int lvl) {
    return lvl == 0 ? 65536 : (lvl == 1 ? 16384 : 4096);
}

static __device__ __forceinline__ unsigned long long shfl_u64(unsigned long long v, int src) {
    int lo = __shfl((int)(unsigned)(v & 0xFFFFFFFFull), src, 64);
    int hi = __shfl((int)(unsigned)(v >> 32), src, 64);
    return ((unsigned long long)(unsigned)hi << 32) | (unsigned)lo;
}

// ---------- kernel 1: exact top-1000 per (img,level) by logit desc, index asc ----------

__global__ __launch_bounds__(256) void k_topk(const float* __restrict__ o2,
                                              const float* __restrict__ o3,
                                              const float* __restrict__ o4,
                                              int* __restrict__ idx_out) {
    const int task = blockIdx.x, img = task / 3, lvl = task % 3;
    const float* obj = lvl == 0 ? o2 : (lvl == 1 ? o3 : o4);
    const int HW = level_hw(lvl);
    const float* base = obj + (size_t)img * 3 * HW;
    const int tid = threadIdx.x;

    __shared__ unsigned hist[256];
    __shared__ unsigned sh_pref;
    __shared__ int sh_kk, sh_cntG, sh_cntE;
    __shared__ unsigned long long comp[1024];
    __shared__ int eqIdx[1024];

    if (tid == 0) { sh_pref = 0u; sh_kk = KSEL; }

    // 4-pass radix select (descending) to find key threshold T and remainder r
    for (int p = 3; p >= 0; --p) {
        hist[tid] = 0u;
        __syncthreads();
        unsigned pref = sh_pref;
        for (int a = 0; a < 3; ++a) {
            const float* pl = base + a * HW;
            for (int pos = tid; pos < HW; pos += 256) {
                unsigned key = fkey(pl[pos]);
                bool ok = (p == 3) || ((key >> (8 * (p + 1))) == pref);
                if (ok) atomicAdd(&hist[(key >> (8 * p)) & 255u], 1u);
            }
        }
        __syncthreads();
        if (tid == 0) {
            unsigned cum = 0; int kk = sh_kk; int chosen = 0;
            for (int b = 255; b >= 0; --b) {
                unsigned c = hist[b];
                if (cum + c >= (unsigned)kk) { chosen = b; kk -= (int)cum; break; }
                cum += c;
            }
            sh_pref = (sh_pref << 8) | (unsigned)chosen;
            sh_kk = kk;
        }
        __syncthreads();
    }

    const unsigned T = sh_pref;
    const int r = sh_kk;                 // need r lowest-index elements equal to T
    if (tid == 0) { sh_cntG = 0; sh_cntE = 0; }
    for (int t = tid; t < 1024; t += 256) comp[t] = 0ull;
    __syncthreads();

    // compaction: all keys > T, plus collect indices of keys == T
    for (int a = 0; a < 3; ++a) {
        const float* pl = base + a * HW;
        for (int pos = tid; pos < HW; pos += 256) {
            unsigned key = fkey(pl[pos]);
            if (key > T) {
                int slot = atomicAdd(&sh_cntG, 1);
                int i = pos * 3 + a;
                comp[slot] = ((unsigned long long)key << 32) | (unsigned)(~(unsigned)i);
            } else if (key == T) {
                int e = atomicAdd(&sh_cntE, 1);
                if (e < 1024) { eqIdx[e] = pos * 3 + a; }
            }
        }
    }
    __syncthreads();

    if (tid == 0) {
        int ne = sh_cntE; if (ne > 1024) ne = 1024;
        int g = sh_cntG;                 // == KSEL - r by construction
        for (int t = 0; t < r; ++t) {    // selection of r smallest indices among ==T
            int mb = t;
            for (int q = t + 1; q < ne; ++q) if (eqIdx[q] < eqIdx[mb]) mb = q;
            int tmp = eqIdx[t]; eqIdx[t] = eqIdx[mb]; eqIdx[mb] = tmp;
            comp[g + t] = ((unsigned long long)T << 32) | (unsigned)(~(unsigned)eqIdx[t]);
        }
    }
    __syncthreads();

    // bitonic sort 1024 u64, descending -> (key desc, index asc)
    for (unsigned k = 2; k <= 1024; k <<= 1) {
        for (unsigned j = k >> 1; j > 0; j >>= 1) {
            for (unsigned i = tid; i < 1024; i += 256) {
                unsigned ixj = i ^ j;
                if (ixj > i) {
                    unsigned long long A = comp[i], B = comp[ixj];
                    bool desc = ((i & k) == 0);
                    if ((A < B) == desc) { comp[i] = B; comp[ixj] = A; }
                }
            }
            __syncthreads();
        }
    }

    for (int t = tid; t < KSEL; t += 256)
        idx_out[task * KSEL + t] = (int)(~(unsigned)(comp[t] & 0xFFFFFFFFull));
}

// ---------- kernel 2: decode + clip + validity + sigmoid score (all double) ----------

__global__ __launch_bounds__(256) void k_decode(const float* __restrict__ o2, const float* __restrict__ o3, const float* __restrict__ o4,
                                                const float* __restrict__ g2, const float* __restrict__ g3, const float* __restrict__ g4,
                                                const float* __restrict__ a2, const float* __restrict__ a3, const float* __restrict__ a4,
                                                const int* __restrict__ idx,
                                                double* __restrict__ boxes, double* __restrict__ score, int* __restrict__ valid) {
    const int task = blockIdx.x, img = task / 3, lvl = task % 3;
    const float* obj = lvl == 0 ? o2 : (lvl == 1 ? o3 : o4);
    const float* brg = lvl == 0 ? g2 : (lvl == 1 ? g3 : g4);
    const float* anc = lvl == 0 ? a2 : (lvl == 1 ? a3 : a4);
    const int HW = level_hw(lvl);
    const int N = HW * 3;
    const double XC = 4.135166556742356;   // log(1000/16) in double

    for (int r = threadIdx.x; r < KSEL; r += 256) {
        int i = idx[task * KSEL + r];
        int a = i % 3, pos = i / 3;
        double x = (double)obj[(size_t)img * 3 * HW + (size_t)a * HW + pos];
        double s = 1.0 / (1.0 + exp(-x));

        const float* bb = brg + (size_t)img * 12 * HW + (size_t)(a * 4) * HW + pos;
        double dx = (double)bb[0];
        double dy = (double)bb[(size_t)HW];
        double dw = (double)bb[(size_t)2 * HW];
        double dh = (double)bb[(size_t)3 * HW];

        const float* an = anc + ((size_t)img * N + (size_t)i) * 4;
        double ax1 = an[0], ay1 = an[1], ax2 = an[2], ay2 = an[3];

        double w = ax2 - ax1 + 1.0, h = ay2 - ay1 + 1.0;
        double cx = ax1 + 0.5 * w, cy = ay1 + 0.5 * h;
        if (dw > XC) dw = XC;
        if (dh > XC) dh = XC;
        double pcx = dx * w + cx, pcy = dy * h + cy;
        double pw = exp(dw) * w, ph = exp(dh) * h;
        double x1 = pcx - 0.5 * pw, y1 = pcy - 0.5 * ph;
        double x2 = pcx + 0.5 * pw - 1.0, y2 = pcy + 0.5 * ph - 1.0;
        x1 = fmin(fmax(x1, 0.0), 1023.0);
        y1 = fmin(fmax(y1, 0.0), 1023.0);
        x2 = fmin(fmax(x2, 0.0), 1023.0);
        y2 = fmin(fmax(y2, 0.0), 1023.0);
        double ws_ = x2 - x1 + 1.0, hs_ = y2 - y1 + 1.0;
        double xc = x1 + ws_ / 2.0, yc = y1 + hs_ / 2.0;
        int v = (ws_ >= 0.0) && (hs_ >= 0.0) && (xc < 1024.0) && (yc < 1024.0);

        double* bo = boxes + (size_t)(task * KSEL + r) * 4;
        bo[0] = x1; bo[1] = y1; bo[2] = x2; bo[3] = y2;
        score[task * KSEL + r] = s;
        valid[task * KSEL + r] = v;
    }
}

// ---------- kernel 3: suppression bitmask (iou > 0.7, j > i) ----------

__global__ __launch_bounds__(256) void k_mask(const double* __restrict__ boxes,
                                              unsigned long long* __restrict__ mask) {
    const int task = blockIdx.x;
    __shared__ double bx[KSEL * 4];
    __shared__ double ar[KSEL];
    const double* B = boxes + (size_t)task * KSEL * 4;
    for (int t = threadIdx.x; t < KSEL * 4; t += 256) bx[t] = B[t];
    __syncthreads();
    for (int t = threadIdx.x; t < KSEL; t += 256)
        ar[t] = (bx[t * 4 + 2] - bx[t * 4 + 0] + 1.0) * (bx[t * 4 + 3] - bx[t * 4 + 1] + 1.0);
    __syncthreads();

    const int tbeg = blockIdx.y * 2000;
    for (int t = tbeg + threadIdx.x; t < tbeg + 2000; t += 256) {
        int i = t >> 4, w = t & 15;
        double x1 = bx[i * 4], y1 = bx[i * 4 + 1], x2 = bx[i * 4 + 2], y2 = bx[i * 4 + 3];
        double ai = ar[i];
        unsigned long long m = 0ull;
        int j0 = w * 64;
        int jend = j0 + 64; if (jend > KSEL) jend = KSEL;
        int js = j0; if (js <= i) js = i + 1;
        for (int j = js; j < jend; ++j) {
            double xx1 = fmax(x1, bx[j * 4]);
            double yy1 = fmax(y1, bx[j * 4 + 1]);
            double xx2 = fmin(x2, bx[j * 4 + 2]);
            double yy2 = fmin(y2, bx[j * 4 + 3]);
            double iw = xx2 - xx1 + 1.0; iw = iw > 0.0 ? iw : 0.0;
            double ih = yy2 - yy1 + 1.0; ih = ih > 0.0 ? ih : 0.0;
            double inter = iw * ih;
            double iou = inter / (ai + ar[j] - inter);
            if (iou > 0.7) m |= 1ull << (j - j0);
        }
        mask[(size_t)task * 16000 + t] = m;
    }
}

// ---------- kernel 4: sequential greedy NMS + post-NMS stable reorder ----------

__global__ __launch_bounds__(64) void k_nms(const unsigned long long* __restrict__ mask,
                                            const int* __restrict__ valid,
                                            const double* __restrict__ score,
                                            int* __restrict__ order, double* __restrict__ s2) {
    const int task = blockIdx.x;
    const int lane = threadIdx.x;
    unsigned long long keep = 0ull;
    if (lane < 16) {
        for (int b = 0; b < 64; ++b) {
            int j = lane * 64 + b;
            if (j < KSEL && valid[task * KSEL + j]) keep |= 1ull << b;
        }
    }
    const unsigned long long* M = mask + (size_t)task * 16000;
    for (int i = 0; i < KSEL; ++i) {
        unsigned long long kw = shfl_u64(keep, i >> 6);
        if ((kw >> (i & 63)) & 1ull) {
            if (lane < 16) keep &= ~M[i * 16 + lane];
        }
    }
    __shared__ unsigned long long kws[16];
    if (lane < 16) kws[lane] = keep;
    __syncthreads();
    if (lane == 0) {
        int c = 0;
        for (int j = 0; j < KSEL; ++j)
            if ((kws[j >> 6] >> (j & 63)) & 1ull) {
                order[task * KSEL + c] = j;
                s2[task * KSEL + c] = score[task * KSEL + j];
                ++c;
            }
        for (int j = 0; j < KSEL; ++j)
            if (!((kws[j >> 6] >> (j & 63)) & 1ull)) {
                order[task * KSEL + c] = j;
                s2[task * KSEL + c] = NEG_INF_D;
                ++c;
            }
    }
}

// ---------- kernel 5: per-image merge of 3 levels, final top-1000, level assign ----------

__global__ __launch_bounds__(256) void k_final(const double* __restrict__ boxes,
                                               const double* __restrict__ s2,
                                               const int* __restrict__ order,
                                               float* __restrict__ out) {
    const int img = blockIdx.x;
    const int tid = threadIdx.x;
    __shared__ unsigned long long skey[4096];
    __shared__ int sidx[4096];

    for (int t = tid; t < 4096; t += 256) {
        if (t < 3000) {
            int l = t / 1000, r = t - l * 1000;
            double s = s2[(img * 3 + l) * KSEL + r];
            skey[t] = dkey(s);
            sidx[t] = t;
        } else {
            skey[t] = 0ull;      // below every real key
            sidx[t] = t;
        }
    }
    __syncthreads();

    // bitonic sort 4096 by (key desc, idx asc)
    for (unsigned k = 2; k <= 4096; k <<= 1) {
        for (unsigned j = k >> 1; j > 0; j >>= 1) {
            for (unsigned i = tid; i < 4096; i += 256) {
                unsigned ixj = i ^ j;
                if (ixj > i) {
                    unsigned long long ka = skey[i], kb = skey[ixj];
                    int ia = sidx[i], ib = sidx[ixj];
                    bool bef = (ka > kb) || (ka == kb && ia < ib);
                    bool asc = ((i & k) == 0);
                    if (asc ? !bef : bef) {
                        skey[i] = kb; skey[ixj] = ka;
                        sidx[i] = ib; sidx[ixj] = ia;
                    }
                }
            }
            __syncthreads();
        }
    }

    for (int r = tid; r < KSEL; r += 256) {
        int e = sidx[r];
        int l = e / 1000, rr = e - l * 1000;
        int task = img * 3 + l;
        int pos = order[task * KSEL + rr];
        const double* bo = boxes + (size_t)(task * KSEL + pos) * 4;
        double b0 = bo[0], b1 = bo[1], b2 = bo[2], b3 = bo[3];
        double s = s2[task * KSEL + rr];

        float* fb = out + ((size_t)img * KSEL + r) * 4;
        fb[0] = (float)b0; fb[1] = (float)b1; fb[2] = (float)b2; fb[3] = (float)b3;
        out[8 * KSEL * 4 + img * KSEL + r] = (float)s;

        double area = (b2 - b0 + 1.0) * (b3 - b1 + 1.0);
        double lv = floor(4.0 + log2(sqrt(area) / 224.0 + 1e-6));
        if (!(lv >= 2.0)) lv = 2.0;   // clip low (also catches NaN)
        if (lv > 5.0) lv = 5.0;
        out[8 * KSEL * 5 + img * KSEL + r] = (float)lv;
    }
}

// ---------- launch ----------

extern "C" void kernel_launch(void* const* d_in, const int* in_sizes, int n_in,
                              void* d_out, int out_size, void* d_ws, size_t ws_size,
                              hipStream_t stream) {
    const float* o2 = (const float*)d_in[0];
    const float* o3 = (const float*)d_in[1];
    const float* o4 = (const float*)d_in[2];
    const float* g2 = (const float*)d_in[3];
    const float* g3 = (const float*)d_in[4];
    const float* g4 = (const float*)d_in[5];
    const float* a2 = (const float*)d_in[6];
    const float* a3 = (const float*)d_in[7];
    const float* a4 = (const float*)d_in[8];

    char* ws = (char*)d_ws;
    int*                idx   = (int*)(ws + 0);          //  96,000 B
    int*                valid = (int*)(ws + 96000);      //  96,000 B
    double*             score = (double*)(ws + 192000);  // 192,000 B
    double*             boxes = (double*)(ws + 384000);  // 768,000 B
    int*                order = (int*)(ws + 1152000);    //  96,000 B
    double*             s2    = (double*)(ws + 1248000); // 192,000 B
    unsigned long long* mask  = (unsigned long long*)(ws + 1440000); // 3,072,000 B

    k_topk<<<NTASK, 256, 0, stream>>>(o2, o3, o4, idx);
    k_decode<<<NTASK, 256, 0, stream>>>(o2, o3, o4, g2, g3, g4, a2, a3, a4,
                                        idx, boxes, score, valid);
    k_mask<<<dim3(NTASK, 8), 256, 0, stream>>>(boxes, mask);
    k_nms<<<NTASK, 64, 0, stream>>>(mask, valid, score, order, s2);
    k_final<<<NIMG, 256, 0, stream>>>(boxes, s2, order, (float*)d_out);
}

// Round 2
// 934.212 us; speedup vs baseline: 1.4354x; 1.4354x over previous
//
#include <hip/hip_runtime.h>

#define NTASK 24
#define KSEL 1000
#define NIMG 8
#define NEG_INF_D (-1e30)
#define CAND_CAP 2048

// ---------- helpers ----------

// monotone map: float -> u32 preserving numeric order
static __device__ __forceinline__ unsigned fkey(float x) {
    unsigned u = __float_as_uint(x);
    return u ^ ((u >> 31) ? 0xFFFFFFFFu : 0x80000000u);
}

// monotone map: double -> u64 preserving numeric order
static __device__ __forceinline__ unsigned long long dkey(double d) {
    unsigned long long u = (unsigned long long)__double_as_longlong(d);
    if (u >> 63) u = ~u; else u |= 0x8000000000000000ull;
    return u;
}

static __device__ __forceinline__ int level_hw(int lvl) {
    return lvl == 0 ? 65536 : (lvl == 1 ? 16384 : 4096);
}

static __device__ __forceinline__ unsigned long long shfl_u64(unsigned long long v, int src) {
    int lo = __shfl((int)(unsigned)(v & 0xFFFFFFFFull), src, 64);
    int hi = __shfl((int)(unsigned)(v >> 32), src, 64);
    return ((unsigned long long)(unsigned)hi << 32) | (unsigned)lo;
}

// ---------- phase 1: per-task 4096-bin histogram of top-12 key bits ----------

__global__ __launch_bounds__(256) void k_hist(const float* __restrict__ o2,
                                              const float* __restrict__ o3,
                                              const float* __restrict__ o4,
                                              unsigned* __restrict__ hist) {
    const int task = blockIdx.x, img = task / 3, lvl = task % 3;
    const float* obj = lvl == 0 ? o2 : (lvl == 1 ? o3 : o4);
    const int HW = level_hw(lvl);
    const int total = 3 * HW;
    const float* base = obj + (size_t)img * total;
    const int tid = threadIdx.x;

    __shared__ unsigned h[4096];
    for (int t = tid; t < 4096; t += 256) h[t] = 0u;
    __syncthreads();

    const int per = total / 32;          // 6144 / 1536 / 384, all divisible
    const int beg = blockIdx.y * per;
    for (int t = beg + tid; t < beg + per; t += 256) {
        unsigned key = fkey(base[t]);
        atomicAdd(&h[key >> 20], 1u);
    }
    __syncthreads();

    unsigned* H = hist + task * 4096;
    for (int t = tid; t < 4096; t += 256)
        if (h[t]) atomicAdd(&H[t], h[t]);
}

// ---------- phase 2: find threshold bin B (bins >= B contain >= K elements, > B contain < K) ----------

__global__ __launch_bounds__(256) void k_thresh(const unsigned* __restrict__ hist,
                                                int* __restrict__ thrBin) {
    const int task = blockIdx.x, tid = threadIdx.x;
    __shared__ unsigned h[4096];
    __shared__ unsigned part[256];
    const unsigned* H = hist + task * 4096;
    for (int t = tid; t < 4096; t += 256) h[t] = H[t];
    __syncthreads();
    unsigned s = 0;
    for (int q = 0; q < 16; ++q) s += h[tid * 16 + q];
    part[tid] = s;
    __syncthreads();
    if (tid == 0) {
        unsigned cum = 0;
        int c = 255;
        for (; c >= 0; --c) {
            if (cum + part[c] >= (unsigned)KSEL) break;
            cum += part[c];
        }
        if (c < 0) c = 0;
        int bin = 0;
        for (int b = c * 16 + 15; b >= c * 16; --b) {
            if (cum + h[b] >= (unsigned)KSEL) { bin = b; break; }
            cum += h[b];
        }
        thrBin[task] = bin;
    }
}

// ---------- phase 3: compact candidates (bin >= B) ----------

__global__ __launch_bounds__(256) void k_compact(const float* __restrict__ o2,
                                                 const float* __restrict__ o3,
                                                 const float* __restrict__ o4,
                                                 const int* __restrict__ thrBin,
                                                 unsigned* __restrict__ cnt,
                                                 unsigned long long* __restrict__ cand) {
    const int task = blockIdx.x, img = task / 3, lvl = task % 3;
    const float* obj = lvl == 0 ? o2 : (lvl == 1 ? o3 : o4);
    const int HW = level_hw(lvl);
    const int total = 3 * HW;
    const float* base = obj + (size_t)img * total;
    const unsigned B = (unsigned)thrBin[task];

    const int per = total / 32;
    const int beg = blockIdx.y * per;
    for (int t = beg + threadIdx.x; t < beg + per; t += 256) {
        unsigned key = fkey(base[t]);
        if ((key >> 20) >= B) {
            unsigned slot = atomicAdd(&cnt[task], 1u);
            if (slot < CAND_CAP) {
                int a = t / HW, pos = t - a * HW;
                int i = pos * 3 + a;
                cand[task * CAND_CAP + slot] =
                    ((unsigned long long)key << 32) | (unsigned)(~(unsigned)i);
            }
        }
    }
}

// ---------- phase 4: sort candidates, emit exact top-1000 (key desc, index asc) ----------

__global__ __launch_bounds__(256) void k_sel(const unsigned* __restrict__ cnt,
                                             const unsigned long long* __restrict__ cand,
                                             int* __restrict__ idx_out) {
    const int task = blockIdx.x, tid = threadIdx.x;
    __shared__ unsigned long long comp[CAND_CAP];
    int n = (int)cnt[task]; if (n > CAND_CAP) n = CAND_CAP;
    for (int t = tid; t < CAND_CAP; t += 256)
        comp[t] = (t < n) ? cand[task * CAND_CAP + t] : 0ull;
    __syncthreads();

    for (unsigned k = 2; k <= CAND_CAP; k <<= 1) {
        for (unsigned j = k >> 1; j > 0; j >>= 1) {
            for (unsigned i = tid; i < CAND_CAP; i += 256) {
                unsigned ixj = i ^ j;
                if (ixj > i) {
                    unsigned long long A = comp[i], Bv = comp[ixj];
                    bool desc = ((i & k) == 0);
                    if ((A < Bv) == desc) { comp[i] = Bv; comp[ixj] = A; }
                }
            }
            __syncthreads();
        }
    }

    for (int t = tid; t < KSEL; t += 256)
        idx_out[task * KSEL + t] = (int)(~(unsigned)(comp[t] & 0xFFFFFFFFull));
}

// ---------- kernel 2: decode + clip + validity + sigmoid score (all double) ----------

__global__ __launch_bounds__(256) void k_decode(const float* __restrict__ o2, const float* __restrict__ o3, const float* __restrict__ o4,
                                                const float* __restrict__ g2, const float* __restrict__ g3, const float* __restrict__ g4,
                                                const float* __restrict__ a2, const float* __restrict__ a3, const float* __restrict__ a4,
                                                const int* __restrict__ idx,
                                                double* __restrict__ boxes, double* __restrict__ score, int* __restrict__ valid) {
    const int task = blockIdx.x, img = task / 3, lvl = task % 3;
    const float* obj = lvl == 0 ? o2 : (lvl == 1 ? o3 : o4);
    const float* brg = lvl == 0 ? g2 : (lvl == 1 ? g3 : g4);
    const float* anc = lvl == 0 ? a2 : (lvl == 1 ? a3 : a4);
    const int HW = level_hw(lvl);
    const int N = HW * 3;
    const double XC = 4.135166556742356;   // log(1000/16) in double

    for (int r = threadIdx.x; r < KSEL; r += 256) {
        int i = idx[task * KSEL + r];
        int a = i % 3, pos = i / 3;
        double x = (double)obj[(size_t)img * 3 * HW + (size_t)a * HW + pos];
        double s = 1.0 / (1.0 + exp(-x));

        const float* bb = brg + (size_t)img * 12 * HW + (size_t)(a * 4) * HW + pos;
        double dx = (double)bb[0];
        double dy = (double)bb[(size_t)HW];
        double dw = (double)bb[(size_t)2 * HW];
        double dh = (double)bb[(size_t)3 * HW];

        const float* an = anc + ((size_t)img * N + (size_t)i) * 4;
        double ax1 = an[0], ay1 = an[1], ax2 = an[2], ay2 = an[3];

        double w = ax2 - ax1 + 1.0, h = ay2 - ay1 + 1.0;
        double cx = ax1 + 0.5 * w, cy = ay1 + 0.5 * h;
        if (dw > XC) dw = XC;
        if (dh > XC) dh = XC;
        double pcx = dx * w + cx, pcy = dy * h + cy;
        double pw = exp(dw) * w, ph = exp(dh) * h;
        double x1 = pcx - 0.5 * pw, y1 = pcy - 0.5 * ph;
        double x2 = pcx + 0.5 * pw - 1.0, y2 = pcy + 0.5 * ph - 1.0;
        x1 = fmin(fmax(x1, 0.0), 1023.0);
        y1 = fmin(fmax(y1, 0.0), 1023.0);
        x2 = fmin(fmax(x2, 0.0), 1023.0);
        y2 = fmin(fmax(y2, 0.0), 1023.0);
        double ws_ = x2 - x1 + 1.0, hs_ = y2 - y1 + 1.0;
        double xc = x1 + ws_ / 2.0, yc = y1 + hs_ / 2.0;
        int v = (ws_ >= 0.0) && (hs_ >= 0.0) && (xc < 1024.0) && (yc < 1024.0);

        double* bo = boxes + (size_t)(task * KSEL + r) * 4;
        bo[0] = x1; bo[1] = y1; bo[2] = x2; bo[3] = y2;
        score[task * KSEL + r] = s;
        valid[task * KSEL + r] = v;
    }
}

// ---------- kernel 3: suppression bitmask (iou > 0.7, j > i) ----------

__global__ __launch_bounds__(256) void k_mask(const double* __restrict__ boxes,
                                              unsigned long long* __restrict__ mask) {
    const int task = blockIdx.x;
    __shared__ double bx[KSEL * 4];
    __shared__ double ar[KSEL];
    const double* B = boxes + (size_t)task * KSEL * 4;
    for (int t = threadIdx.x; t < KSEL * 4; t += 256) bx[t] = B[t];
    __syncthreads();
    for (int t = threadIdx.x; t < KSEL; t += 256)
        ar[t] = (bx[t * 4 + 2] - bx[t * 4 + 0] + 1.0) * (bx[t * 4 + 3] - bx[t * 4 + 1] + 1.0);
    __syncthreads();

    const int tbeg = blockIdx.y * 2000;
    for (int t = tbeg + threadIdx.x; t < tbeg + 2000; t += 256) {
        int i = t >> 4, w = t & 15;
        double x1 = bx[i * 4], y1 = bx[i * 4 + 1], x2 = bx[i * 4 + 2], y2 = bx[i * 4 + 3];
        double ai = ar[i];
        unsigned long long m = 0ull;
        int j0 = w * 64;
        int jend = j0 + 64; if (jend > KSEL) jend = KSEL;
        int js = j0; if (js <= i) js = i + 1;
        for (int j = js; j < jend; ++j) {
            double xx1 = fmax(x1, bx[j * 4]);
            double yy1 = fmax(y1, bx[j * 4 + 1]);
            double xx2 = fmin(x2, bx[j * 4 + 2]);
            double yy2 = fmin(y2, bx[j * 4 + 3]);
            double iw = xx2 - xx1 + 1.0; iw = iw > 0.0 ? iw : 0.0;
            double ih = yy2 - yy1 + 1.0; ih = ih > 0.0 ? ih : 0.0;
            double inter = iw * ih;
            double iou = inter / (ai + ar[j] - inter);
            if (iou > 0.7) m |= 1ull << (j - j0);
        }
        mask[(size_t)task * 16000 + t] = m;
    }
}

// ---------- kernel 4: sequential greedy NMS + post-NMS stable reorder ----------

__global__ __launch_bounds__(64) void k_nms(const unsigned long long* __restrict__ mask,
                                            const int* __restrict__ valid,
                                            const double* __restrict__ score,
                                            int* __restrict__ order, double* __restrict__ s2) {
    const int task = blockIdx.x;
    const int lane = threadIdx.x;
    unsigned long long keep = 0ull;
    if (lane < 16) {
        for (int b = 0; b < 64; ++b) {
            int j = lane * 64 + b;
            if (j < KSEL && valid[task * KSEL + j]) keep |= 1ull << b;
        }
    }
    const unsigned long long* M = mask + (size_t)task * 16000;
    for (int i = 0; i < KSEL; ++i) {
        unsigned long long kw = shfl_u64(keep, i >> 6);
        if ((kw >> (i & 63)) & 1ull) {
            if (lane < 16) keep &= ~M[i * 16 + lane];
        }
    }
    __shared__ unsigned long long kws[16];
    if (lane < 16) kws[lane] = keep;
    __syncthreads();
    if (lane == 0) {
        int c = 0;
        for (int j = 0; j < KSEL; ++j)
            if ((kws[j >> 6] >> (j & 63)) & 1ull) {
                order[task * KSEL + c] = j;
                s2[task * KSEL + c] = score[task * KSEL + j];
                ++c;
            }
        for (int j = 0; j < KSEL; ++j)
            if (!((kws[j >> 6] >> (j & 63)) & 1ull)) {
                order[task * KSEL + c] = j;
                s2[task * KSEL + c] = NEG_INF_D;
                ++c;
            }
    }
}

// ---------- kernel 5: per-image merge of 3 levels, final top-1000, level assign ----------

__global__ __launch_bounds__(256) void k_final(const double* __restrict__ boxes,
                                               const double* __restrict__ s2,
                                               const int* __restrict__ order,
                                               float* __restrict__ out) {
    const int img = blockIdx.x;
    const int tid = threadIdx.x;
    __shared__ unsigned long long skey[4096];
    __shared__ int sidx[4096];

    for (int t = tid; t < 4096; t += 256) {
        if (t < 3000) {
            int l = t / 1000, r = t - l * 1000;
            double s = s2[(img * 3 + l) * KSEL + r];
            skey[t] = dkey(s);
            sidx[t] = t;
        } else {
            skey[t] = 0ull;      // below every real key
            sidx[t] = t;
        }
    }
    __syncthreads();

    // bitonic sort 4096 by (key desc, idx asc)
    for (unsigned k = 2; k <= 4096; k <<= 1) {
        for (unsigned j = k >> 1; j > 0; j >>= 1) {
            for (unsigned i = tid; i < 4096; i += 256) {
                unsigned ixj = i ^ j;
                if (ixj > i) {
                    unsigned long long ka = skey[i], kb = skey[ixj];
                    int ia = sidx[i], ib = sidx[ixj];
                    bool bef = (ka > kb) || (ka == kb && ia < ib);
                    bool asc = ((i & k) == 0);
                    if (asc ? !bef : bef) {
                        skey[i] = kb; skey[ixj] = ka;
                        sidx[i] = ib; sidx[ixj] = ia;
                    }
                }
            }
            __syncthreads();
        }
    }

    for (int r = tid; r < KSEL; r += 256) {
        int e = sidx[r];
        int l = e / 1000, rr = e - l * 1000;
        int task = img * 3 + l;
        int pos = order[task * KSEL + rr];
        const double* bo = boxes + (size_t)(task * KSEL + pos) * 4;
        double b0 = bo[0], b1 = bo[1], b2 = bo[2], b3 = bo[3];
        double s = s2[task * KSEL + rr];

        float* fb = out + ((size_t)img * KSEL + r) * 4;
        fb[0] = (float)b0; fb[1] = (float)b1; fb[2] = (float)b2; fb[3] = (float)b3;
        out[8 * KSEL * 4 + img * KSEL + r] = (float)s;

        double area = (b2 - b0 + 1.0) * (b3 - b1 + 1.0);
        double lv = floor(4.0 + log2(sqrt(area) / 224.0 + 1e-6));
        if (!(lv >= 2.0)) lv = 2.0;   // clip low (also catches NaN)
        if (lv > 5.0) lv = 5.0;
        out[8 * KSEL * 5 + img * KSEL + r] = (float)lv;
    }
}

// ---------- launch ----------

extern "C" void kernel_launch(void* const* d_in, const int* in_sizes, int n_in,
                              void* d_out, int out_size, void* d_ws, size_t ws_size,
                              hipStream_t stream) {
    const float* o2 = (const float*)d_in[0];
    const float* o3 = (const float*)d_in[1];
    const float* o4 = (const float*)d_in[2];
    const float* g2 = (const float*)d_in[3];
    const float* g3 = (const float*)d_in[4];
    const float* g4 = (const float*)d_in[5];
    const float* a2 = (const float*)d_in[6];
    const float* a3 = (const float*)d_in[7];
    const float* a4 = (const float*)d_in[8];

    char* ws = (char*)d_ws;
    int*                idx   = (int*)(ws + 0);          //  96,000 B
    int*                valid = (int*)(ws + 96000);      //  96,000 B
    double*             score = (double*)(ws + 192000);  // 192,000 B
    double*             boxes = (double*)(ws + 384000);  // 768,000 B
    int*                order = (int*)(ws + 1152000);    //  96,000 B
    double*             s2    = (double*)(ws + 1248000); // 192,000 B
    char*               maskR = ws + 1440000;            // 3,072,000 B (shared region)
    unsigned long long* mask  = (unsigned long long*)maskR;

    // top-k scratch aliases the mask region (dead until k_mask writes it)
    unsigned*           hist   = (unsigned*)(maskR + 0);        // 393,216 B
    unsigned*           cnt    = (unsigned*)(maskR + 393216);   //      96 B
    int*                thrBin = (int*)(maskR + 393312);        //      96 B
    unsigned long long* cand   = (unsigned long long*)(maskR + 393472); // 393,216 B

    hipMemsetAsync(maskR, 0, 393312, stream);   // zero hist + cnt

    k_hist<<<dim3(NTASK, 32), 256, 0, stream>>>(o2, o3, o4, hist);
    k_thresh<<<NTASK, 256, 0, stream>>>(hist, thrBin);
    k_compact<<<dim3(NTASK, 32), 256, 0, stream>>>(o2, o3, o4, thrBin, cnt, cand);
    k_sel<<<NTASK, 256, 0, stream>>>(cnt, cand, idx);

    k_decode<<<NTASK, 256, 0, stream>>>(o2, o3, o4, g2, g3, g4, a2, a3, a4,
                                        idx, boxes, score, valid);
    k_mask<<<dim3(NTASK, 8), 256, 0, stream>>>(boxes, mask);
    k_nms<<<NTASK, 64, 0, stream>>>(mask, valid, score, order, s2);
    k_final<<<NIMG, 256, 0, stream>>>(boxes, s2, order, (float*)d_out);
}

// Round 3
// 700.037 us; speedup vs baseline: 1.9155x; 1.3345x over previous
//
#include <hip/hip_runtime.h>

#define NTASK 24
#define KSEL 1000
#define NIMG 8
#define NEG_INF_D (-1e30)
#define CAND_CAP 2048

// ---------- helpers ----------

static __device__ __forceinline__ unsigned fkey(float x) {
    unsigned u = __float_as_uint(x);
    return u ^ ((u >> 31) ? 0xFFFFFFFFu : 0x80000000u);
}

static __device__ __forceinline__ unsigned long long dkey(double d) {
    unsigned long long u = (unsigned long long)__double_as_longlong(d);
    if (u >> 63) u = ~u; else u |= 0x8000000000000000ull;
    return u;
}

static __device__ __forceinline__ int level_hw(int lvl) {
    return lvl == 0 ? 65536 : (lvl == 1 ? 16384 : 4096);
}

static __device__ __forceinline__ unsigned long long shfl_u64(unsigned long long v, int src) {
    int lo = __shfl((int)(unsigned)(v & 0xFFFFFFFFull), src, 64);
    int hi = __shfl((int)(unsigned)(v >> 32), src, 64);
    return ((unsigned long long)(unsigned)hi << 32) | (unsigned)lo;
}

// ---------- phase 1: per-task 4096-bin histogram of top-12 key bits ----------

__global__ __launch_bounds__(256) void k_hist(const float* __restrict__ o2,
                                              const float* __restrict__ o3,
                                              const float* __restrict__ o4,
                                              unsigned* __restrict__ hist) {
    const int task = blockIdx.x, img = task / 3, lvl = task % 3;
    const float* obj = lvl == 0 ? o2 : (lvl == 1 ? o3 : o4);
    const int HW = level_hw(lvl);
    const int total = 3 * HW;
    const float* base = obj + (size_t)img * total;
    const int tid = threadIdx.x;

    __shared__ unsigned h[4096];
    for (int t = tid; t < 4096; t += 256) h[t] = 0u;
    __syncthreads();

    const int per = total / 32;
    const int beg = blockIdx.y * per;
    for (int t = beg + tid; t < beg + per; t += 256) {
        unsigned key = fkey(base[t]);
        atomicAdd(&h[key >> 20], 1u);
    }
    __syncthreads();

    unsigned* H = hist + task * 4096;
    for (int t = tid; t < 4096; t += 256)
        if (h[t]) atomicAdd(&H[t], h[t]);
}

// ---------- phase 2: threshold bin ----------

__global__ __launch_bounds__(256) void k_thresh(const unsigned* __restrict__ hist,
                                                int* __restrict__ thrBin) {
    const int task = blockIdx.x, tid = threadIdx.x;
    __shared__ unsigned h[4096];
    __shared__ unsigned part[256];
    const unsigned* H = hist + task * 4096;
    for (int t = tid; t < 4096; t += 256) h[t] = H[t];
    __syncthreads();
    unsigned s = 0;
    for (int q = 0; q < 16; ++q) s += h[tid * 16 + q];
    part[tid] = s;
    __syncthreads();
    if (tid == 0) {
        unsigned cum = 0;
        int c = 255;
        for (; c >= 0; --c) {
            if (cum + part[c] >= (unsigned)KSEL) break;
            cum += part[c];
        }
        if (c < 0) c = 0;
        int bin = 0;
        for (int b = c * 16 + 15; b >= c * 16; --b) {
            if (cum + h[b] >= (unsigned)KSEL) { bin = b; break; }
            cum += h[b];
        }
        thrBin[task] = bin;
    }
}

// ---------- phase 3: compact candidates ----------

__global__ __launch_bounds__(256) void k_compact(const float* __restrict__ o2,
                                                 const float* __restrict__ o3,
                                                 const float* __restrict__ o4,
                                                 const int* __restrict__ thrBin,
                                                 unsigned* __restrict__ cnt,
                                                 unsigned long long* __restrict__ cand) {
    const int task = blockIdx.x, img = task / 3, lvl = task % 3;
    const float* obj = lvl == 0 ? o2 : (lvl == 1 ? o3 : o4);
    const int HW = level_hw(lvl);
    const int total = 3 * HW;
    const float* base = obj + (size_t)img * total;
    const unsigned B = (unsigned)thrBin[task];

    const int per = total / 32;
    const int beg = blockIdx.y * per;
    for (int t = beg + threadIdx.x; t < beg + per; t += 256) {
        unsigned key = fkey(base[t]);
        if ((key >> 20) >= B) {
            unsigned slot = atomicAdd(&cnt[task], 1u);
            if (slot < CAND_CAP) {
                int a = t / HW, pos = t - a * HW;
                int i = pos * 3 + a;
                cand[task * CAND_CAP + slot] =
                    ((unsigned long long)key << 32) | (unsigned)(~(unsigned)i);
            }
        }
    }
}

// ---------- phase 4: sort candidates, emit exact top-1000 ----------

__global__ __launch_bounds__(256) void k_sel(const unsigned* __restrict__ cnt,
                                             const unsigned long long* __restrict__ cand,
                                             int* __restrict__ idx_out) {
    const int task = blockIdx.x, tid = threadIdx.x;
    __shared__ unsigned long long comp[CAND_CAP];
    int n = (int)cnt[task]; if (n > CAND_CAP) n = CAND_CAP;
    for (int t = tid; t < CAND_CAP; t += 256)
        comp[t] = (t < n) ? cand[task * CAND_CAP + t] : 0ull;
    __syncthreads();

    for (unsigned k = 2; k <= CAND_CAP; k <<= 1) {
        for (unsigned j = k >> 1; j > 0; j >>= 1) {
            for (unsigned i = tid; i < CAND_CAP; i += 256) {
                unsigned ixj = i ^ j;
                if (ixj > i) {
                    unsigned long long A = comp[i], Bv = comp[ixj];
                    bool desc = ((i & k) == 0);
                    if ((A < Bv) == desc) { comp[i] = Bv; comp[ixj] = A; }
                }
            }
            __syncthreads();
        }
    }

    for (int t = tid; t < KSEL; t += 256)
        idx_out[task * KSEL + t] = (int)(~(unsigned)(comp[t] & 0xFFFFFFFFull));
}

// ---------- fused: decode + mask(LDS) + greedy NMS + compaction ----------

__global__ __launch_bounds__(1024) void k_nmsfull(
    const float* __restrict__ o2, const float* __restrict__ o3, const float* __restrict__ o4,
    const float* __restrict__ g2, const float* __restrict__ g3, const float* __restrict__ g4,
    const float* __restrict__ a2, const float* __restrict__ a3, const float* __restrict__ a4,
    const int* __restrict__ idx,
    double* __restrict__ boxes, double* __restrict__ score,
    int* __restrict__ order, double* __restrict__ s2) {

    const int task = blockIdx.x, img = task / 3, lvl = task % 3;
    const float* obj = lvl == 0 ? o2 : (lvl == 1 ? o3 : o4);
    const float* brg = lvl == 0 ? g2 : (lvl == 1 ? g3 : g4);
    const float* anc = lvl == 0 ? a2 : (lvl == 1 ? a3 : a4);
    const int HW = level_hw(lvl);
    const int N = HW * 3;
    const double XC = 4.135166556742356;   // log(1000/16)

    __shared__ unsigned long long Msh[16000];   // 128,000 B suppression mask
    __shared__ unsigned long long kws[16];
    __shared__ int prefK[16], prefN[16], totKsh;

    const int tid = threadIdx.x;
    for (int t = tid; t < 16000; t += 1024) Msh[t] = 0ull;
    if (tid < 16) kws[tid] = 0ull;
    __syncthreads();

    // ---- phase A: decode + clip + validity + sigmoid (double) ----
    if (tid < KSEL) {
        int i = idx[task * KSEL + tid];
        int a = i % 3, pos = i / 3;
        double x = (double)obj[(size_t)img * 3 * HW + (size_t)a * HW + pos];
        double s = 1.0 / (1.0 + exp(-x));

        const float* bb = brg + (size_t)img * 12 * HW + (size_t)(a * 4) * HW + pos;
        double dx = (double)bb[0];
        double dy = (double)bb[(size_t)HW];
        double dw = (double)bb[(size_t)2 * HW];
        double dh = (double)bb[(size_t)3 * HW];

        const float* an = anc + ((size_t)img * N + (size_t)i) * 4;
        double ax1 = an[0], ay1 = an[1], ax2 = an[2], ay2 = an[3];

        double w = ax2 - ax1 + 1.0, h = ay2 - ay1 + 1.0;
        double cx = ax1 + 0.5 * w, cy = ay1 + 0.5 * h;
        if (dw > XC) dw = XC;
        if (dh > XC) dh = XC;
        double pcx = dx * w + cx, pcy = dy * h + cy;
        double pw = exp(dw) * w, ph = exp(dh) * h;
        double x1 = pcx - 0.5 * pw, y1 = pcy - 0.5 * ph;
        double x2 = pcx + 0.5 * pw - 1.0, y2 = pcy + 0.5 * ph - 1.0;
        x1 = fmin(fmax(x1, 0.0), 1023.0);
        y1 = fmin(fmax(y1, 0.0), 1023.0);
        x2 = fmin(fmax(x2, 0.0), 1023.0);
        y2 = fmin(fmax(y2, 0.0), 1023.0);
        double ws_ = x2 - x1 + 1.0, hs_ = y2 - y1 + 1.0;
        double xc = x1 + ws_ / 2.0, yc = y1 + hs_ / 2.0;
        bool v = (ws_ >= 0.0) && (hs_ >= 0.0) && (xc < 1024.0) && (yc < 1024.0);

        double* bo = boxes + (size_t)(task * KSEL + tid) * 4;
        bo[0] = x1; bo[1] = y1; bo[2] = x2; bo[3] = y2;
        score[task * KSEL + tid] = s;
        if (v) atomicOr(&kws[tid >> 6], 1ull << (tid & 63));
    }
    __syncthreads();

    // ---- phase B: suppression mask into LDS, wave-tiled 64x64, ballot per row ----
    const double* B = boxes + (size_t)task * KSEL * 4;
    const int wid = tid >> 6, lane = tid & 63;
    for (int t = wid; t < 136; t += 16) {           // triangular (I,J), J >= I
        int I = 0, rem = t;
        while (rem >= 16 - I) { rem -= 16 - I; ++I; }
        const int J = I + rem;
        const int j = J * 64 + lane;
        const int jc = j < KSEL ? j : KSEL - 1;
        double jx1 = B[jc * 4 + 0], jy1 = B[jc * 4 + 1];
        double jx2 = B[jc * 4 + 2], jy2 = B[jc * 4 + 3];
        double aj = (jx2 - jx1 + 1.0) * (jy2 - jy1 + 1.0);
        int iend = I * 64 + 64; if (iend > KSEL) iend = KSEL;
        for (int i = I * 64; i < iend; ++i) {
            double ix1 = B[i * 4 + 0], iy1 = B[i * 4 + 1];
            double ix2 = B[i * 4 + 2], iy2 = B[i * 4 + 3];
            double ai = (ix2 - ix1 + 1.0) * (iy2 - iy1 + 1.0);
            double xx1 = fmax(ix1, jx1), yy1 = fmax(iy1, jy1);
            double xx2 = fmin(ix2, jx2), yy2 = fmin(iy2, jy2);
            double iw = xx2 - xx1 + 1.0; iw = iw > 0.0 ? iw : 0.0;
            double ih = yy2 - yy1 + 1.0; ih = ih > 0.0 ? ih : 0.0;
            double inter = iw * ih;
            double iou = inter / (ai + aj - inter);
            bool sup = (j > i) && (j < KSEL) && (iou > 0.7);
            unsigned long long m = __ballot(sup);
            if (lane == 0) Msh[i * 16 + J] = m;
        }
    }
    __syncthreads();

    // ---- phase C: serial greedy NMS over LDS mask (wave 0) ----
    if (tid < 64) {
        unsigned long long keep = (lane < 16) ? kws[lane] : 0ull;
        for (int i = 0; i < KSEL; ++i) {
            unsigned long long kw = shfl_u64(keep, i >> 6);
            if ((kw >> (i & 63)) & 1ull) {
                if (lane < 16) keep &= ~Msh[i * 16 + lane];
            }
        }
        if (lane < 16) kws[lane] = keep;
    }
    __syncthreads();

    // ---- phase D: prefix sums ----
    if (tid == 0) {
        int pk = 0, pn = 0;
        for (int l = 0; l < 16; ++l) {
            prefK[l] = pk; prefN[l] = pn;
            int limit = KSEL - 64 * l; if (limit > 64) limit = 64;
            int kb = (int)__popcll(kws[l]);
            pk += kb; pn += limit - kb;
        }
        totKsh = pk;
    }
    __syncthreads();

    // ---- phase E: compaction (kept in index order, then suppressed) ----
    if (tid < 16) {
        unsigned long long kw = kws[tid];
        int limit = KSEL - 64 * tid; if (limit > 64) limit = 64;
        int ck = prefK[tid], cn = totKsh + prefN[tid];
        for (int b = 0; b < limit; ++b) {
            int j = tid * 64 + b;
            if ((kw >> b) & 1ull) {
                order[task * KSEL + ck] = j;
                s2[task * KSEL + ck] = score[task * KSEL + j];
                ++ck;
            } else {
                order[task * KSEL + cn] = j;
                s2[task * KSEL + cn] = NEG_INF_D;
                ++cn;
            }
        }
    }
}

// ---------- kernel 5: per-image merge, final top-1000, level assign ----------

__global__ __launch_bounds__(256) void k_final(const double* __restrict__ boxes,
                                               const double* __restrict__ s2,
                                               const int* __restrict__ order,
                                               float* __restrict__ out) {
    const int img = blockIdx.x;
    const int tid = threadIdx.x;
    __shared__ unsigned long long skey[4096];
    __shared__ int sidx[4096];

    for (int t = tid; t < 4096; t += 256) {
        if (t < 3000) {
            int l = t / 1000, r = t - l * 1000;
            double s = s2[(img * 3 + l) * KSEL + r];
            skey[t] = dkey(s);
            sidx[t] = t;
        } else {
            skey[t] = 0ull;
            sidx[t] = t;
        }
    }
    __syncthreads();

    for (unsigned k = 2; k <= 4096; k <<= 1) {
        for (unsigned j = k >> 1; j > 0; j >>= 1) {
            for (unsigned i = tid; i < 4096; i += 256) {
                unsigned ixj = i ^ j;
                if (ixj > i) {
                    unsigned long long ka = skey[i], kb = skey[ixj];
                    int ia = sidx[i], ib = sidx[ixj];
                    bool bef = (ka > kb) || (ka == kb && ia < ib);
                    bool asc = ((i & k) == 0);
                    if (asc ? !bef : bef) {
                        skey[i] = kb; skey[ixj] = ka;
                        sidx[i] = ib; sidx[ixj] = ia;
                    }
                }
            }
            __syncthreads();
        }
    }

    for (int r = tid; r < KSEL; r += 256) {
        int e = sidx[r];
        int l = e / 1000, rr = e - l * 1000;
        int task = img * 3 + l;
        int pos = order[task * KSEL + rr];
        const double* bo = boxes + (size_t)(task * KSEL + pos) * 4;
        double b0 = bo[0], b1 = bo[1], b2 = bo[2], b3 = bo[3];
        double s = s2[task * KSEL + rr];

        float* fb = out + ((size_t)img * KSEL + r) * 4;
        fb[0] = (float)b0; fb[1] = (float)b1; fb[2] = (float)b2; fb[3] = (float)b3;
        out[8 * KSEL * 4 + img * KSEL + r] = (float)s;

        double area = (b2 - b0 + 1.0) * (b3 - b1 + 1.0);
        double lv = floor(4.0 + log2(sqrt(area) / 224.0 + 1e-6));
        if (!(lv >= 2.0)) lv = 2.0;
        if (lv > 5.0) lv = 5.0;
        out[8 * KSEL * 5 + img * KSEL + r] = (float)lv;
    }
}

// ---------- launch ----------

extern "C" void kernel_launch(void* const* d_in, const int* in_sizes, int n_in,
                              void* d_out, int out_size, void* d_ws, size_t ws_size,
                              hipStream_t stream) {
    const float* o2 = (const float*)d_in[0];
    const float* o3 = (const float*)d_in[1];
    const float* o4 = (const float*)d_in[2];
    const float* g2 = (const float*)d_in[3];
    const float* g3 = (const float*)d_in[4];
    const float* g4 = (const float*)d_in[5];
    const float* a2 = (const float*)d_in[6];
    const float* a3 = (const float*)d_in[7];
    const float* a4 = (const float*)d_in[8];

    char* ws = (char*)d_ws;
    int*                idx   = (int*)(ws + 0);          //  96,000 B
    double*             score = (double*)(ws + 192000);  // 192,000 B
    double*             boxes = (double*)(ws + 384000);  // 768,000 B
    int*                order = (int*)(ws + 1152000);    //  96,000 B
    double*             s2    = (double*)(ws + 1248000); // 192,000 B
    char*               scr   = ws + 1440000;            // top-k scratch region

    unsigned*           hist   = (unsigned*)(scr + 0);        // 393,216 B
    unsigned*           cnt    = (unsigned*)(scr + 393216);   //      96 B
    int*                thrBin = (int*)(scr + 393312);        //      96 B
    unsigned long long* cand   = (unsigned long long*)(scr + 393472); // 393,216 B

    hipMemsetAsync(scr, 0, 393312, stream);   // zero hist + cnt

    k_hist<<<dim3(NTASK, 32), 256, 0, stream>>>(o2, o3, o4, hist);
    k_thresh<<<NTASK, 256, 0, stream>>>(hist, thrBin);
    k_compact<<<dim3(NTASK, 32), 256, 0, stream>>>(o2, o3, o4, thrBin, cnt, cand);
    k_sel<<<NTASK, 256, 0, stream>>>(cnt, cand, idx);

    k_nmsfull<<<NTASK, 1024, 0, stream>>>(o2, o3, o4, g2, g3, g4, a2, a3, a4,
                                          idx, boxes, score, order, s2);
    k_final<<<NIMG, 256, 0, stream>>>(boxes, s2, order, (float*)d_out);
}

// Round 4
// 486.143 us; speedup vs baseline: 2.7583x; 1.4400x over previous
//
#include <hip/hip_runtime.h>

#define NTASK 24
#define KSEL 1000
#define NIMG 8
#define NEG_INF_D (-1e30)
#define CAND_CAP 2048

// ---------- helpers ----------

static __device__ __forceinline__ unsigned fkey(float x) {
    unsigned u = __float_as_uint(x);
    return u ^ ((u >> 31) ? 0xFFFFFFFFu : 0x80000000u);
}

static __device__ __forceinline__ unsigned long long dkey(double d) {
    unsigned long long u = (unsigned long long)__double_as_longlong(d);
    if (u >> 63) u = ~u; else u |= 0x8000000000000000ull;
    return u;
}

static __device__ __forceinline__ int level_hw(int lvl) {
    return lvl == 0 ? 65536 : (lvl == 1 ? 16384 : 4096);
}

static __device__ __forceinline__ unsigned long long shfl_u64(unsigned long long v, int src) {
    int lo = __shfl((int)(unsigned)(v & 0xFFFFFFFFull), src, 64);
    int hi = __shfl((int)(unsigned)(v >> 32), src, 64);
    return ((unsigned long long)(unsigned)hi << 32) | (unsigned)lo;
}

static __device__ __forceinline__ unsigned long long shfl_xor_u64(unsigned long long v, int m) {
    int lo = __shfl_xor((int)(unsigned)(v & 0xFFFFFFFFull), m, 64);
    int hi = __shfl_xor((int)(unsigned)(v >> 32), m, 64);
    return ((unsigned long long)(unsigned)hi << 32) | (unsigned)lo;
}

// ---------- phase 1: per-task 4096-bin histogram of top-12 key bits ----------

__global__ __launch_bounds__(256) void k_hist(const float* __restrict__ o2,
                                              const float* __restrict__ o3,
                                              const float* __restrict__ o4,
                                              unsigned* __restrict__ hist) {
    const int task = blockIdx.x, img = task / 3, lvl = task % 3;
    const float* obj = lvl == 0 ? o2 : (lvl == 1 ? o3 : o4);
    const int HW = level_hw(lvl);
    const int total = 3 * HW;
    const float* base = obj + (size_t)img * total;
    const int tid = threadIdx.x;

    __shared__ unsigned h[4096];
    for (int t = tid; t < 4096; t += 256) h[t] = 0u;
    __syncthreads();

    const int per = total / 32;
    const int beg = blockIdx.y * per;
    for (int t = beg + tid; t < beg + per; t += 256) {
        unsigned key = fkey(base[t]);
        atomicAdd(&h[key >> 20], 1u);
    }
    __syncthreads();

    unsigned* H = hist + task * 4096;
    for (int t = tid; t < 4096; t += 256)
        if (h[t]) atomicAdd(&H[t], h[t]);
}

// ---------- phase 2: threshold bin ----------

__global__ __launch_bounds__(256) void k_thresh(const unsigned* __restrict__ hist,
                                                int* __restrict__ thrBin) {
    const int task = blockIdx.x, tid = threadIdx.x;
    __shared__ unsigned h[4096];
    __shared__ unsigned part[256];
    const unsigned* H = hist + task * 4096;
    for (int t = tid; t < 4096; t += 256) h[t] = H[t];
    __syncthreads();
    unsigned s = 0;
    for (int q = 0; q < 16; ++q) s += h[tid * 16 + q];
    part[tid] = s;
    __syncthreads();
    if (tid == 0) {
        unsigned cum = 0;
        int c = 255;
        for (; c >= 0; --c) {
            if (cum + part[c] >= (unsigned)KSEL) break;
            cum += part[c];
        }
        if (c < 0) c = 0;
        int bin = 0;
        for (int b = c * 16 + 15; b >= c * 16; --b) {
            if (cum + h[b] >= (unsigned)KSEL) { bin = b; break; }
            cum += h[b];
        }
        thrBin[task] = bin;
    }
}

// ---------- phase 3: compact candidates ----------

__global__ __launch_bounds__(256) void k_compact(const float* __restrict__ o2,
                                                 const float* __restrict__ o3,
                                                 const float* __restrict__ o4,
                                                 const int* __restrict__ thrBin,
                                                 unsigned* __restrict__ cnt,
                                                 unsigned long long* __restrict__ cand) {
    const int task = blockIdx.x, img = task / 3, lvl = task % 3;
    const float* obj = lvl == 0 ? o2 : (lvl == 1 ? o3 : o4);
    const int HW = level_hw(lvl);
    const int total = 3 * HW;
    const float* base = obj + (size_t)img * total;
    const unsigned B = (unsigned)thrBin[task];

    const int per = total / 32;
    const int beg = blockIdx.y * per;
    for (int t = beg + threadIdx.x; t < beg + per; t += 256) {
        unsigned key = fkey(base[t]);
        if ((key >> 20) >= B) {
            unsigned slot = atomicAdd(&cnt[task], 1u);
            if (slot < CAND_CAP) {
                int a = t / HW, pos = t - a * HW;
                int i = pos * 3 + a;
                cand[task * CAND_CAP + slot] =
                    ((unsigned long long)key << 32) | (unsigned)(~(unsigned)i);
            }
        }
    }
}

// ---------- phase 4: sort candidates, emit exact top-1000 ----------

__global__ __launch_bounds__(256) void k_sel(const unsigned* __restrict__ cnt,
                                             const unsigned long long* __restrict__ cand,
                                             int* __restrict__ idx_out) {
    const int task = blockIdx.x, tid = threadIdx.x;
    __shared__ unsigned long long comp[CAND_CAP];
    int n = (int)cnt[task]; if (n > CAND_CAP) n = CAND_CAP;
    for (int t = tid; t < CAND_CAP; t += 256)
        comp[t] = (t < n) ? cand[task * CAND_CAP + t] : 0ull;
    __syncthreads();

    for (unsigned k = 2; k <= CAND_CAP; k <<= 1) {
        for (unsigned j = k >> 1; j > 0; j >>= 1) {
            for (unsigned i = tid; i < CAND_CAP; i += 256) {
                unsigned ixj = i ^ j;
                if (ixj > i) {
                    unsigned long long A = comp[i], Bv = comp[ixj];
                    bool desc = ((i & k) == 0);
                    if ((A < Bv) == desc) { comp[i] = Bv; comp[ixj] = A; }
                }
            }
            __syncthreads();
        }
    }

    for (int t = tid; t < KSEL; t += 256)
        idx_out[task * KSEL + t] = (int)(~(unsigned)(comp[t] & 0xFFFFFFFFull));
}

// ---------- decode + clip + validity + sigmoid (double) ----------

__global__ __launch_bounds__(256) void k_decode(const float* __restrict__ o2, const float* __restrict__ o3, const float* __restrict__ o4,
                                                const float* __restrict__ g2, const float* __restrict__ g3, const float* __restrict__ g4,
                                                const float* __restrict__ a2, const float* __restrict__ a3, const float* __restrict__ a4,
                                                const int* __restrict__ idx,
                                                double* __restrict__ boxes, double* __restrict__ score, int* __restrict__ valid) {
    const int task = blockIdx.x, img = task / 3, lvl = task % 3;
    const float* obj = lvl == 0 ? o2 : (lvl == 1 ? o3 : o4);
    const float* brg = lvl == 0 ? g2 : (lvl == 1 ? g3 : g4);
    const float* anc = lvl == 0 ? a2 : (lvl == 1 ? a3 : a4);
    const int HW = level_hw(lvl);
    const int N = HW * 3;
    const double XC = 4.135166556742356;   // log(1000/16)

    const int r = blockIdx.y * 250 + threadIdx.x;
    if (threadIdx.x < 250 && r < KSEL) {
        int i = idx[task * KSEL + r];
        int a = i % 3, pos = i / 3;
        double x = (double)obj[(size_t)img * 3 * HW + (size_t)a * HW + pos];
        double s = 1.0 / (1.0 + exp(-x));

        const float* bb = brg + (size_t)img * 12 * HW + (size_t)(a * 4) * HW + pos;
        double dx = (double)bb[0];
        double dy = (double)bb[(size_t)HW];
        double dw = (double)bb[(size_t)2 * HW];
        double dh = (double)bb[(size_t)3 * HW];

        const float* an = anc + ((size_t)img * N + (size_t)i) * 4;
        double ax1 = an[0], ay1 = an[1], ax2 = an[2], ay2 = an[3];

        double w = ax2 - ax1 + 1.0, h = ay2 - ay1 + 1.0;
        double cx = ax1 + 0.5 * w, cy = ay1 + 0.5 * h;
        if (dw > XC) dw = XC;
        if (dh > XC) dh = XC;
        double pcx = dx * w + cx, pcy = dy * h + cy;
        double pw = exp(dw) * w, ph = exp(dh) * h;
        double x1 = pcx - 0.5 * pw, y1 = pcy - 0.5 * ph;
        double x2 = pcx + 0.5 * pw - 1.0, y2 = pcy + 0.5 * ph - 1.0;
        x1 = fmin(fmax(x1, 0.0), 1023.0);
        y1 = fmin(fmax(y1, 0.0), 1023.0);
        x2 = fmin(fmax(x2, 0.0), 1023.0);
        y2 = fmin(fmax(y2, 0.0), 1023.0);
        double ws_ = x2 - x1 + 1.0, hs_ = y2 - y1 + 1.0;
        double xc = x1 + ws_ / 2.0, yc = y1 + hs_ / 2.0;
        int v = (ws_ >= 0.0) && (hs_ >= 0.0) && (xc < 1024.0) && (yc < 1024.0);

        double* bo = boxes + (size_t)(task * KSEL + r) * 4;
        bo[0] = x1; bo[1] = y1; bo[2] = x2; bo[3] = y2;
        score[task * KSEL + r] = s;
        valid[task * KSEL + r] = v;
    }
}

// ---------- suppression mask, transposed layout maskT[task][J][i], one wave per 64x64 tile ----------

__global__ __launch_bounds__(512) void k_mask(const double* __restrict__ boxes,
                                              unsigned long long* __restrict__ maskT) {
    const int task = blockIdx.x;
    const int wid = threadIdx.x >> 6, lane = threadIdx.x & 63;
    const int t = blockIdx.y * 8 + wid;          // 17*8 = 136 triangular tiles
    if (t >= 136) return;
    int I = 0, rem = t;
    while (rem >= 16 - I) { rem -= 16 - I; ++I; }
    const int J = I + rem;

    const double* B = boxes + (size_t)task * KSEL * 4;
    const int j = J * 64 + lane;
    const int jc = j < KSEL ? j : KSEL - 1;
    double jx1 = B[jc * 4 + 0], jy1 = B[jc * 4 + 1];
    double jx2 = B[jc * 4 + 2], jy2 = B[jc * 4 + 3];
    double aj = (jx2 - jx1 + 1.0) * (jy2 - jy1 + 1.0);

    unsigned long long* MT = maskT + (size_t)task * 16000 + (size_t)J * KSEL;
    int iend = I * 64 + 64; if (iend > KSEL) iend = KSEL;
    for (int i = I * 64; i < iend; ++i) {
        double ix1 = B[i * 4 + 0], iy1 = B[i * 4 + 1];
        double ix2 = B[i * 4 + 2], iy2 = B[i * 4 + 3];
        double ai = (ix2 - ix1 + 1.0) * (iy2 - iy1 + 1.0);
        double xx1 = fmax(ix1, jx1), yy1 = fmax(iy1, jy1);
        double xx2 = fmin(ix2, jx2), yy2 = fmin(iy2, jy2);
        double iw = xx2 - xx1 + 1.0; iw = iw > 0.0 ? iw : 0.0;
        double ih = yy2 - yy1 + 1.0; ih = ih > 0.0 ? ih : 0.0;
        double inter = iw * ih;
        double iou = inter / (ai + aj - inter);
        bool sup = (j > i) && (j < KSEL) && (iou > 0.7);
        unsigned long long m = __ballot(sup);
        if (lane == 0) MT[i] = m;
    }
}

// ---------- chunked greedy NMS + compaction ----------

__global__ __launch_bounds__(1024) void k_nms(const unsigned long long* __restrict__ maskT,
                                              const int* __restrict__ valid,
                                              const double* __restrict__ score,
                                              int* __restrict__ order, double* __restrict__ s2) {
    const int task = blockIdx.x;
    const int tid = threadIdx.x;
    const int wid = tid >> 6, lane = tid & 63;
    const unsigned long long* MT = maskT + (size_t)task * 16000;

    __shared__ unsigned long long kws[16];
    __shared__ int prefK[16], prefN[16], totKsh;

    if (tid < 16) kws[tid] = 0ull;
    __syncthreads();
    if (tid < KSEL && valid[task * KSEL + tid])
        atomicOr(&kws[tid >> 6], 1ull << (tid & 63));
    __syncthreads();

    // sequential chunks; inside chunk: register shfl chain; then parallel apply
    for (int c = 0; c < 16; ++c) {
        if (wid == 0) {
            const int row = c * 64 + lane;
            unsigned long long m = (row < KSEL) ? MT[(size_t)c * KSEL + row] : 0ull;
            unsigned long long k = kws[c];
#pragma unroll 16
            for (int b = 0; b < 64; ++b) {
                unsigned long long tmp = shfl_u64(m, b);
                if ((k >> b) & 1ull) k &= ~tmp;
            }
            if (lane == 0) kws[c] = k;
        }
        __syncthreads();
        if (wid > c) {
            const int row = c * 64 + lane;           // c <= 14 here, row < 960 < KSEL
            unsigned long long kc = kws[c];
            unsigned long long m = ((kc >> lane) & 1ull) ? MT[(size_t)wid * KSEL + row] : 0ull;
#pragma unroll
            for (int off = 1; off < 64; off <<= 1) m |= shfl_xor_u64(m, off);
            if (lane == 0) kws[wid] &= ~m;
        }
        __syncthreads();
    }

    // prefix sums
    if (tid == 0) {
        int pk = 0, pn = 0;
        for (int l = 0; l < 16; ++l) {
            prefK[l] = pk; prefN[l] = pn;
            int limit = KSEL - 64 * l; if (limit > 64) limit = 64;
            int kb = (int)__popcll(kws[l]);
            pk += kb; pn += limit - kb;
        }
        totKsh = pk;
    }
    __syncthreads();

    // compaction (kept in index order, then suppressed)
    if (tid < 16) {
        unsigned long long kw = kws[tid];
        int limit = KSEL - 64 * tid; if (limit > 64) limit = 64;
        int ck = prefK[tid], cn = totKsh + prefN[tid];
        for (int b = 0; b < limit; ++b) {
            int j = tid * 64 + b;
            if ((kw >> b) & 1ull) {
                order[task * KSEL + ck] = j;
                s2[task * KSEL + ck] = score[task * KSEL + j];
                ++ck;
            } else {
                order[task * KSEL + cn] = j;
                s2[task * KSEL + cn] = NEG_INF_D;
                ++cn;
            }
        }
    }
}

// ---------- per-image merge, final top-1000, level assign ----------

__global__ __launch_bounds__(256) void k_final(const double* __restrict__ boxes,
                                               const double* __restrict__ s2,
                                               const int* __restrict__ order,
                                               float* __restrict__ out) {
    const int img = blockIdx.x;
    const int tid = threadIdx.x;
    __shared__ unsigned long long skey[4096];
    __shared__ int sidx[4096];

    for (int t = tid; t < 4096; t += 256) {
        if (t < 3000) {
            int l = t / 1000, r = t - l * 1000;
            double s = s2[(img * 3 + l) * KSEL + r];
            skey[t] = dkey(s);
            sidx[t] = t;
        } else {
            skey[t] = 0ull;
            sidx[t] = t;
        }
    }
    __syncthreads();

    for (unsigned k = 2; k <= 4096; k <<= 1) {
        for (unsigned j = k >> 1; j > 0; j >>= 1) {
            for (unsigned i = tid; i < 4096; i += 256) {
                unsigned ixj = i ^ j;
                if (ixj > i) {
                    unsigned long long ka = skey[i], kb = skey[ixj];
                    int ia = sidx[i], ib = sidx[ixj];
                    bool bef = (ka > kb) || (ka == kb && ia < ib);
                    bool asc = ((i & k) == 0);
                    if (asc ? !bef : bef) {
                        skey[i] = kb; skey[ixj] = ka;
                        sidx[i] = ib; sidx[ixj] = ia;
                    }
                }
            }
            __syncthreads();
        }
    }

    for (int r = tid; r < KSEL; r += 256) {
        int e = sidx[r];
        int l = e / 1000, rr = e - l * 1000;
        int task = img * 3 + l;
        int pos = order[task * KSEL + rr];
        const double* bo = boxes + (size_t)(task * KSEL + pos) * 4;
        double b0 = bo[0], b1 = bo[1], b2 = bo[2], b3 = bo[3];
        double s = s2[task * KSEL + rr];

        float* fb = out + ((size_t)img * KSEL + r) * 4;
        fb[0] = (float)b0; fb[1] = (float)b1; fb[2] = (float)b2; fb[3] = (float)b3;
        out[8 * KSEL * 4 + img * KSEL + r] = (float)s;

        double area = (b2 - b0 + 1.0) * (b3 - b1 + 1.0);
        double lv = floor(4.0 + log2(sqrt(area) / 224.0 + 1e-6));
        if (!(lv >= 2.0)) lv = 2.0;
        if (lv > 5.0) lv = 5.0;
        out[8 * KSEL * 5 + img * KSEL + r] = (float)lv;
    }
}

// ---------- launch ----------

extern "C" void kernel_launch(void* const* d_in, const int* in_sizes, int n_in,
                              void* d_out, int out_size, void* d_ws, size_t ws_size,
                              hipStream_t stream) {
    const float* o2 = (const float*)d_in[0];
    const float* o3 = (const float*)d_in[1];
    const float* o4 = (const float*)d_in[2];
    const float* g2 = (const float*)d_in[3];
    const float* g3 = (const float*)d_in[4];
    const float* g4 = (const float*)d_in[5];
    const float* a2 = (const float*)d_in[6];
    const float* a3 = (const float*)d_in[7];
    const float* a4 = (const float*)d_in[8];

    char* ws = (char*)d_ws;
    int*                idx   = (int*)(ws + 0);          //  96,000 B
    int*                valid = (int*)(ws + 96000);      //  96,000 B
    double*             score = (double*)(ws + 192000);  // 192,000 B
    double*             boxes = (double*)(ws + 384000);  // 768,000 B
    int*                order = (int*)(ws + 1152000);    //  96,000 B
    double*             s2    = (double*)(ws + 1248000); // 192,000 B
    char*               scr   = ws + 1440000;            // 3,072,000 B shared region

    // top-k scratch (dead after k_sel)
    unsigned*           hist   = (unsigned*)(scr + 0);        // 393,216 B
    unsigned*           cnt    = (unsigned*)(scr + 393216);   //      96 B
    int*                thrBin = (int*)(scr + 393312);        //      96 B
    unsigned long long* cand   = (unsigned long long*)(scr + 393472); // 393,216 B
    // mask region aliases the same space (written by k_mask after k_sel)
    unsigned long long* maskT  = (unsigned long long*)scr;    // 3,072,000 B

    hipMemsetAsync(scr, 0, 393312, stream);   // zero hist + cnt

    k_hist<<<dim3(NTASK, 32), 256, 0, stream>>>(o2, o3, o4, hist);
    k_thresh<<<NTASK, 256, 0, stream>>>(hist, thrBin);
    k_compact<<<dim3(NTASK, 32), 256, 0, stream>>>(o2, o3, o4, thrBin, cnt, cand);
    k_sel<<<NTASK, 256, 0, stream>>>(cnt, cand, idx);

    k_decode<<<dim3(NTASK, 4), 256, 0, stream>>>(o2, o3, o4, g2, g3, g4, a2, a3, a4,
                                                 idx, boxes, score, valid);
    k_mask<<<dim3(NTASK, 17), 512, 0, stream>>>(boxes, maskT);
    k_nms<<<NTASK, 1024, 0, stream>>>(maskT, valid, score, order, s2);
    k_final<<<NIMG, 256, 0, stream>>>(boxes, s2, order, (float*)d_out);
}

// Round 5
// 279.132 us; speedup vs baseline: 4.8039x; 1.7416x over previous
//
#include <hip/hip_runtime.h>

#define NTASK 24
#define KSEL 1000
#define NIMG 8
#define NEG_INF_D (-1e30)
#define CAND_CAP 2048

// ---------- helpers ----------

static __device__ __forceinline__ unsigned fkey(float x) {
    unsigned u = __float_as_uint(x);
    return u ^ ((u >> 31) ? 0xFFFFFFFFu : 0x80000000u);
}

static __device__ __forceinline__ unsigned long long dkey(double d) {
    unsigned long long u = (unsigned long long)__double_as_longlong(d);
    if (u >> 63) u = ~u; else u |= 0x8000000000000000ull;
    return u;
}

static __device__ __forceinline__ int level_hw(int lvl) {
    return lvl == 0 ? 65536 : (lvl == 1 ? 16384 : 4096);
}

static __device__ __forceinline__ unsigned long long shfl_u64(unsigned long long v, int src) {
    int lo = __shfl((int)(unsigned)(v & 0xFFFFFFFFull), src, 64);
    int hi = __shfl((int)(unsigned)(v >> 32), src, 64);
    return ((unsigned long long)(unsigned)hi << 32) | (unsigned)lo;
}

static __device__ __forceinline__ unsigned long long shfl_xor_u64(unsigned long long v, int m) {
    int lo = __shfl_xor((int)(unsigned)(v & 0xFFFFFFFFull), m, 64);
    int hi = __shfl_xor((int)(unsigned)(v >> 32), m, 64);
    return ((unsigned long long)(unsigned)hi << 32) | (unsigned)lo;
}

// ---------- phase 1: per-task 4096-bin histogram of top-12 key bits ----------

__global__ __launch_bounds__(256) void k_hist(const float* __restrict__ o2,
                                              const float* __restrict__ o3,
                                              const float* __restrict__ o4,
                                              unsigned* __restrict__ hist) {
    const int task = blockIdx.x, img = task / 3, lvl = task % 3;
    const float* obj = lvl == 0 ? o2 : (lvl == 1 ? o3 : o4);
    const int HW = level_hw(lvl);
    const int total = 3 * HW;
    const float* base = obj + (size_t)img * total;
    const int tid = threadIdx.x;

    __shared__ unsigned h[4096];
    for (int t = tid; t < 4096; t += 256) h[t] = 0u;
    __syncthreads();

    const int per = total / 32;
    const int beg = blockIdx.y * per;
    for (int t = beg + tid; t < beg + per; t += 256) {
        unsigned key = fkey(base[t]);
        atomicAdd(&h[key >> 20], 1u);
    }
    __syncthreads();

    unsigned* H = hist + task * 4096;
    for (int t = tid; t < 4096; t += 256)
        if (h[t]) atomicAdd(&H[t], h[t]);
}

// ---------- phase 2: threshold bin ----------

__global__ __launch_bounds__(256) void k_thresh(const unsigned* __restrict__ hist,
                                                int* __restrict__ thrBin) {
    const int task = blockIdx.x, tid = threadIdx.x;
    __shared__ unsigned h[4096];
    __shared__ unsigned part[256];
    const unsigned* H = hist + task * 4096;
    for (int t = tid; t < 4096; t += 256) h[t] = H[t];
    __syncthreads();
    unsigned s = 0;
    for (int q = 0; q < 16; ++q) s += h[tid * 16 + q];
    part[tid] = s;
    __syncthreads();
    if (tid == 0) {
        unsigned cum = 0;
        int c = 255;
        for (; c >= 0; --c) {
            if (cum + part[c] >= (unsigned)KSEL) break;
            cum += part[c];
        }
        if (c < 0) c = 0;
        int bin = 0;
        for (int b = c * 16 + 15; b >= c * 16; --b) {
            if (cum + h[b] >= (unsigned)KSEL) { bin = b; break; }
            cum += h[b];
        }
        thrBin[task] = bin;
    }
}

// ---------- phase 3: compact candidates ----------

__global__ __launch_bounds__(256) void k_compact(const float* __restrict__ o2,
                                                 const float* __restrict__ o3,
                                                 const float* __restrict__ o4,
                                                 const int* __restrict__ thrBin,
                                                 unsigned* __restrict__ cnt,
                                                 unsigned long long* __restrict__ cand) {
    const int task = blockIdx.x, img = task / 3, lvl = task % 3;
    const float* obj = lvl == 0 ? o2 : (lvl == 1 ? o3 : o4);
    const int HW = level_hw(lvl);
    const int total = 3 * HW;
    const float* base = obj + (size_t)img * total;
    const unsigned B = (unsigned)thrBin[task];

    const int per = total / 32;
    const int beg = blockIdx.y * per;
    for (int t = beg + threadIdx.x; t < beg + per; t += 256) {
        unsigned key = fkey(base[t]);
        if ((key >> 20) >= B) {
            unsigned slot = atomicAdd(&cnt[task], 1u);
            if (slot < CAND_CAP) {
                int a = t / HW, pos = t - a * HW;
                int i = pos * 3 + a;
                cand[task * CAND_CAP + slot] =
                    ((unsigned long long)key << 32) | (unsigned)(~(unsigned)i);
            }
        }
    }
}

// ---------- phase 4: sort candidates, emit exact top-1000 ----------

__global__ __launch_bounds__(1024) void k_sel(const unsigned* __restrict__ cnt,
                                              const unsigned long long* __restrict__ cand,
                                              int* __restrict__ idx_out) {
    const int task = blockIdx.x, tid = threadIdx.x;
    __shared__ unsigned long long comp[CAND_CAP];
    int n = (int)cnt[task]; if (n > CAND_CAP) n = CAND_CAP;
    for (int t = tid; t < CAND_CAP; t += 1024)
        comp[t] = (t < n) ? cand[task * CAND_CAP + t] : 0ull;
    __syncthreads();

    for (unsigned k = 2; k <= CAND_CAP; k <<= 1) {
        for (unsigned j = k >> 1; j > 0; j >>= 1) {
            for (unsigned i = tid; i < CAND_CAP; i += 1024) {
                unsigned ixj = i ^ j;
                if (ixj > i) {
                    unsigned long long A = comp[i], Bv = comp[ixj];
                    bool desc = ((i & k) == 0);
                    if ((A < Bv) == desc) { comp[i] = Bv; comp[ixj] = A; }
                }
            }
            __syncthreads();
        }
    }

    for (int t = tid; t < KSEL; t += 1024)
        idx_out[task * KSEL + t] = (int)(~(unsigned)(comp[t] & 0xFFFFFFFFull));
}

// ---------- decode + clip + validity + sigmoid (double) ----------

__global__ __launch_bounds__(256) void k_decode(const float* __restrict__ o2, const float* __restrict__ o3, const float* __restrict__ o4,
                                                const float* __restrict__ g2, const float* __restrict__ g3, const float* __restrict__ g4,
                                                const float* __restrict__ a2, const float* __restrict__ a3, const float* __restrict__ a4,
                                                const int* __restrict__ idx,
                                                double* __restrict__ boxes, double* __restrict__ score, int* __restrict__ valid) {
    const int task = blockIdx.x, img = task / 3, lvl = task % 3;
    const float* obj = lvl == 0 ? o2 : (lvl == 1 ? o3 : o4);
    const float* brg = lvl == 0 ? g2 : (lvl == 1 ? g3 : g4);
    const float* anc = lvl == 0 ? a2 : (lvl == 1 ? a3 : a4);
    const int HW = level_hw(lvl);
    const int N = HW * 3;
    const double XC = 4.135166556742356;   // log(1000/16)

    const int r = blockIdx.y * 250 + threadIdx.x;
    if (threadIdx.x < 250 && r < KSEL) {
        int i = idx[task * KSEL + r];
        int a = i % 3, pos = i / 3;
        double x = (double)obj[(size_t)img * 3 * HW + (size_t)a * HW + pos];
        double s = 1.0 / (1.0 + exp(-x));

        const float* bb = brg + (size_t)img * 12 * HW + (size_t)(a * 4) * HW + pos;
        double dx = (double)bb[0];
        double dy = (double)bb[(size_t)HW];
        double dw = (double)bb[(size_t)2 * HW];
        double dh = (double)bb[(size_t)3 * HW];

        const float* an = anc + ((size_t)img * N + (size_t)i) * 4;
        double ax1 = an[0], ay1 = an[1], ax2 = an[2], ay2 = an[3];

        double w = ax2 - ax1 + 1.0, h = ay2 - ay1 + 1.0;
        double cx = ax1 + 0.5 * w, cy = ay1 + 0.5 * h;
        if (dw > XC) dw = XC;
        if (dh > XC) dh = XC;
        double pcx = dx * w + cx, pcy = dy * h + cy;
        double pw = exp(dw) * w, ph = exp(dh) * h;
        double x1 = pcx - 0.5 * pw, y1 = pcy - 0.5 * ph;
        double x2 = pcx + 0.5 * pw - 1.0, y2 = pcy + 0.5 * ph - 1.0;
        x1 = fmin(fmax(x1, 0.0), 1023.0);
        y1 = fmin(fmax(y1, 0.0), 1023.0);
        x2 = fmin(fmax(x2, 0.0), 1023.0);
        y2 = fmin(fmax(y2, 0.0), 1023.0);
        double ws_ = x2 - x1 + 1.0, hs_ = y2 - y1 + 1.0;
        double xc = x1 + ws_ / 2.0, yc = y1 + hs_ / 2.0;
        int v = (ws_ >= 0.0) && (hs_ >= 0.0) && (xc < 1024.0) && (yc < 1024.0);

        double* bo = boxes + (size_t)(task * KSEL + r) * 4;
        bo[0] = x1; bo[1] = y1; bo[2] = x2; bo[3] = y2;
        score[task * KSEL + r] = s;
        valid[task * KSEL + r] = v;
    }
}

// ---------- suppression mask, transposed layout maskT[task][J][i], one wave per 64x64 tile ----------

__global__ __launch_bounds__(512) void k_mask(const double* __restrict__ boxes,
                                              unsigned long long* __restrict__ maskT) {
    const int task = blockIdx.x;
    const int wid = threadIdx.x >> 6, lane = threadIdx.x & 63;
    const int t = blockIdx.y * 8 + wid;          // 17*8 = 136 triangular tiles
    if (t >= 136) return;
    int I = 0, rem = t;
    while (rem >= 16 - I) { rem -= 16 - I; ++I; }
    const int J = I + rem;

    const double* B = boxes + (size_t)task * KSEL * 4;
    const int j = J * 64 + lane;
    const int jc = j < KSEL ? j : KSEL - 1;
    double jx1 = B[jc * 4 + 0], jy1 = B[jc * 4 + 1];
    double jx2 = B[jc * 4 + 2], jy2 = B[jc * 4 + 3];
    double aj = (jx2 - jx1 + 1.0) * (jy2 - jy1 + 1.0);

    unsigned long long* MT = maskT + (size_t)task * 16000 + (size_t)J * KSEL;
    int iend = I * 64 + 64; if (iend > KSEL) iend = KSEL;
    for (int i = I * 64; i < iend; ++i) {
        double ix1 = B[i * 4 + 0], iy1 = B[i * 4 + 1];
        double ix2 = B[i * 4 + 2], iy2 = B[i * 4 + 3];
        double ai = (ix2 - ix1 + 1.0) * (iy2 - iy1 + 1.0);
        double xx1 = fmax(ix1, jx1), yy1 = fmax(iy1, jy1);
        double xx2 = fmin(ix2, jx2), yy2 = fmin(iy2, jy2);
        double iw = xx2 - xx1 + 1.0; iw = iw > 0.0 ? iw : 0.0;
        double ih = yy2 - yy1 + 1.0; ih = ih > 0.0 ? ih : 0.0;
        double inter = iw * ih;
        double iou = inter / (ai + aj - inter);
        bool sup = (j > i) && (j < KSEL) && (iou > 0.7);
        unsigned long long m = __ballot(sup);
        if (lane == 0) MT[i] = m;
    }
}

// ---------- chunked greedy NMS + compaction ----------

__global__ __launch_bounds__(1024) void k_nms(const unsigned long long* __restrict__ maskT,
                                              const int* __restrict__ valid,
                                              const double* __restrict__ score,
                                              int* __restrict__ order, double* __restrict__ s2) {
    const int task = blockIdx.x;
    const int tid = threadIdx.x;
    const int wid = tid >> 6, lane = tid & 63;
    const unsigned long long* MT = maskT + (size_t)task * 16000;

    __shared__ unsigned long long kws[16];
    __shared__ int prefK[16], prefN[16], totKsh;

    if (tid < 16) kws[tid] = 0ull;
    __syncthreads();
    if (tid < KSEL && valid[task * KSEL + tid])
        atomicOr(&kws[tid >> 6], 1ull << (tid & 63));
    __syncthreads();

    // sequential chunks; inside chunk: register shfl chain; then parallel apply
    for (int c = 0; c < 16; ++c) {
        if (wid == 0) {
            const int row = c * 64 + lane;
            unsigned long long m = (row < KSEL) ? MT[(size_t)c * KSEL + row] : 0ull;
            unsigned long long k = kws[c];
#pragma unroll 16
            for (int b = 0; b < 64; ++b) {
                unsigned long long tmp = shfl_u64(m, b);
                if ((k >> b) & 1ull) k &= ~tmp;
            }
            if (lane == 0) kws[c] = k;
        }
        __syncthreads();
        if (wid > c) {
            const int row = c * 64 + lane;           // c <= 14 here, row < 960 < KSEL
            unsigned long long kc = kws[c];
            unsigned long long m = ((kc >> lane) & 1ull) ? MT[(size_t)wid * KSEL + row] : 0ull;
#pragma unroll
            for (int off = 1; off < 64; off <<= 1) m |= shfl_xor_u64(m, off);
            if (lane == 0) kws[wid] &= ~m;
        }
        __syncthreads();
    }

    // prefix sums
    if (tid == 0) {
        int pk = 0, pn = 0;
        for (int l = 0; l < 16; ++l) {
            prefK[l] = pk; prefN[l] = pn;
            int limit = KSEL - 64 * l; if (limit > 64) limit = 64;
            int kb = (int)__popcll(kws[l]);
            pk += kb; pn += limit - kb;
        }
        totKsh = pk;
    }
    __syncthreads();

    // compaction (kept in index order, then suppressed)
    if (tid < 16) {
        unsigned long long kw = kws[tid];
        int limit = KSEL - 64 * tid; if (limit > 64) limit = 64;
        int ck = prefK[tid], cn = totKsh + prefN[tid];
        for (int b = 0; b < limit; ++b) {
            int j = tid * 64 + b;
            if ((kw >> b) & 1ull) {
                order[task * KSEL + ck] = j;
                s2[task * KSEL + ck] = score[task * KSEL + j];
                ++ck;
            } else {
                order[task * KSEL + cn] = j;
                s2[task * KSEL + cn] = NEG_INF_D;
                ++cn;
            }
        }
    }
}

// ---------- per-image 3-way sorted merge (merge-path), final top-1000, level assign ----------
// Each level's s2 list is already descending (kept in rank order, then NEG_INF).
// Reference top_k over the 3000-concat == stable 3-way merge, ties -> lower concat index.

__global__ __launch_bounds__(1024) void k_final(const double* __restrict__ boxes,
                                                const double* __restrict__ s2,
                                                const int* __restrict__ order,
                                                float* __restrict__ out) {
    const int img = blockIdx.x;
    const int tid = threadIdx.x;
    __shared__ unsigned long long Mkey[KSEL];
    __shared__ int Mid[KSEL];                     // 0..1999 = level*1000 + pos

    const double* L0 = s2 + (size_t)(img * 3 + 0) * KSEL;
    const double* L1 = s2 + (size_t)(img * 3 + 1) * KSEL;
    const double* L2 = s2 + (size_t)(img * 3 + 2) * KSEL;

    // ---- phase 1: top-1000 of merge(L0, L1), A(=L0) wins ties ----
    if (tid < KSEL) {
        const int r = tid;
        int lo = 0, hi = r;                       // a in [0, r]
        while (lo < hi) {
            int a = (lo + hi) >> 1;
            // if A[a] comes before B[r-1-a], first r outputs must include A[a]
            if (dkey(L0[a]) >= dkey(L1[r - 1 - a])) lo = a + 1; else hi = a;
        }
        int a = lo, b = r - a;
        unsigned long long ka = dkey(L0[a]), kb = dkey(L1[b]);
        if (ka >= kb) { Mkey[r] = ka; Mid[r] = a; }
        else          { Mkey[r] = kb; Mid[r] = 1000 + b; }
    }
    __syncthreads();

    // ---- phase 2: top-1000 of merge(M, L2), M wins ties ----
    if (tid < KSEL) {
        const int r = tid;
        int lo = 0, hi = r;
        while (lo < hi) {
            int a = (lo + hi) >> 1;
            if (Mkey[a] >= dkey(L2[r - 1 - a])) lo = a + 1; else hi = a;
        }
        int a = lo, b = r - a;
        int e;
        if (a < KSEL && Mkey[a] >= dkey(L2[b])) e = Mid[a];
        else e = 2000 + b;

        int l = e / 1000, rr = e - l * 1000;
        int task = img * 3 + l;
        int pos = order[task * KSEL + rr];
        const double* bo = boxes + (size_t)(task * KSEL + pos) * 4;
        double b0 = bo[0], b1 = bo[1], b2 = bo[2], b3 = bo[3];
        double s = s2[task * KSEL + rr];

        float* fb = out + ((size_t)img * KSEL + r) * 4;
        fb[0] = (float)b0; fb[1] = (float)b1; fb[2] = (float)b2; fb[3] = (float)b3;
        out[8 * KSEL * 4 + img * KSEL + r] = (float)s;

        double area = (b2 - b0 + 1.0) * (b3 - b1 + 1.0);
        double lv = floor(4.0 + log2(sqrt(area) / 224.0 + 1e-6));
        if (!(lv >= 2.0)) lv = 2.0;
        if (lv > 5.0) lv = 5.0;
        out[8 * KSEL * 5 + img * KSEL + r] = (float)lv;
    }
}

// ---------- launch ----------

extern "C" void kernel_launch(void* const* d_in, const int* in_sizes, int n_in,
                              void* d_out, int out_size, void* d_ws, size_t ws_size,
                              hipStream_t stream) {
    const float* o2 = (const float*)d_in[0];
    const float* o3 = (const float*)d_in[1];
    const float* o4 = (const float*)d_in[2];
    const float* g2 = (const float*)d_in[3];
    const float* g3 = (const float*)d_in[4];
    const float* g4 = (const float*)d_in[5];
    const float* a2 = (const float*)d_in[6];
    const float* a3 = (const float*)d_in[7];
    const float* a4 = (const float*)d_in[8];

    char* ws = (char*)d_ws;
    int*                idx   = (int*)(ws + 0);          //  96,000 B
    int*                valid = (int*)(ws + 96000);      //  96,000 B
    double*             score = (double*)(ws + 192000);  // 192,000 B
    double*             boxes = (double*)(ws + 384000);  // 768,000 B
    int*                order = (int*)(ws + 1152000);    //  96,000 B
    double*             s2    = (double*)(ws + 1248000); // 192,000 B
    char*               scr   = ws + 1440000;            // 3,072,000 B shared region

    // top-k scratch (dead after k_sel)
    unsigned*           hist   = (unsigned*)(scr + 0);        // 393,216 B
    unsigned*           cnt    = (unsigned*)(scr + 393216);   //      96 B
    int*                thrBin = (int*)(scr + 393312);        //      96 B
    unsigned long long* cand   = (unsigned long long*)(scr + 393472); // 393,216 B
    // mask region aliases the same space (written by k_mask after k_sel)
    unsigned long long* maskT  = (unsigned long long*)scr;    // 3,072,000 B

    hipMemsetAsync(scr, 0, 393312, stream);   // zero hist + cnt

    k_hist<<<dim3(NTASK, 32), 256, 0, stream>>>(o2, o3, o4, hist);
    k_thresh<<<NTASK, 256, 0, stream>>>(hist, thrBin);
    k_compact<<<dim3(NTASK, 32), 256, 0, stream>>>(o2, o3, o4, thrBin, cnt, cand);
    k_sel<<<NTASK, 1024, 0, stream>>>(cnt, cand, idx);

    k_decode<<<dim3(NTASK, 4), 256, 0, stream>>>(o2, o3, o4, g2, g3, g4, a2, a3, a4,
                                                 idx, boxes, score, valid);
    k_mask<<<dim3(NTASK, 17), 512, 0, stream>>>(boxes, maskT);
    k_nms<<<NTASK, 1024, 0, stream>>>(maskT, valid, score, order, s2);
    k_final<<<NIMG, 1024, 0, stream>>>(boxes, s2, order, (float*)d_out);
}

// Round 6
// 170.655 us; speedup vs baseline: 7.8576x; 1.6357x over previous
//
#include <hip/hip_runtime.h>

#define NTASK 24
#define KSEL 1000
#define NIMG 8
#define NEG_INF_D (-1e30)
#define CAND_CAP 2048

// ---------- helpers ----------

static __device__ __forceinline__ unsigned fkey(float x) {
    unsigned u = __float_as_uint(x);
    return u ^ ((u >> 31) ? 0xFFFFFFFFu : 0x80000000u);
}

static __device__ __forceinline__ unsigned long long dkey(double d) {
    unsigned long long u = (unsigned long long)__double_as_longlong(d);
    if (u >> 63) u = ~u; else u |= 0x8000000000000000ull;
    return u;
}

static __device__ __forceinline__ int level_hw(int lvl) {
    return lvl == 0 ? 65536 : (lvl == 1 ? 16384 : 4096);
}

static __device__ __forceinline__ unsigned long long shfl_u64(unsigned long long v, int src) {
    int lo = __shfl((int)(unsigned)(v & 0xFFFFFFFFull), src, 64);
    int hi = __shfl((int)(unsigned)(v >> 32), src, 64);
    return ((unsigned long long)(unsigned)hi << 32) | (unsigned)lo;
}

static __device__ __forceinline__ unsigned long long shfl_xor_u64(unsigned long long v, int m) {
    int lo = __shfl_xor((int)(unsigned)(v & 0xFFFFFFFFull), m, 64);
    int hi = __shfl_xor((int)(unsigned)(v >> 32), m, 64);
    return ((unsigned long long)(unsigned)hi << 32) | (unsigned)lo;
}

// ---------- phase 1: per-task 4096-bin histogram of top-12 key bits ----------

__global__ __launch_bounds__(256) void k_hist(const float* __restrict__ o2,
                                              const float* __restrict__ o3,
                                              const float* __restrict__ o4,
                                              unsigned* __restrict__ hist) {
    const int task = blockIdx.x, img = task / 3, lvl = task % 3;
    const float* obj = lvl == 0 ? o2 : (lvl == 1 ? o3 : o4);
    const int HW = level_hw(lvl);
    const int total = 3 * HW;
    const float* base = obj + (size_t)img * total;
    const int tid = threadIdx.x;

    __shared__ unsigned h[4096];
    for (int t = tid; t < 4096; t += 256) h[t] = 0u;
    __syncthreads();

    const int per = total / 32;
    const int beg = blockIdx.y * per;
    for (int t = beg + tid; t < beg + per; t += 256) {
        unsigned key = fkey(base[t]);
        atomicAdd(&h[key >> 20], 1u);
    }
    __syncthreads();

    unsigned* H = hist + task * 4096;
    for (int t = tid; t < 4096; t += 256)
        if (h[t]) atomicAdd(&H[t], h[t]);
}

// ---------- phase 2: threshold bin ----------

__global__ __launch_bounds__(256) void k_thresh(const unsigned* __restrict__ hist,
                                                int* __restrict__ thrBin) {
    const int task = blockIdx.x, tid = threadIdx.x;
    __shared__ unsigned h[4096];
    __shared__ unsigned part[256];
    const unsigned* H = hist + task * 4096;
    for (int t = tid; t < 4096; t += 256) h[t] = H[t];
    __syncthreads();
    unsigned s = 0;
    for (int q = 0; q < 16; ++q) s += h[tid * 16 + q];
    part[tid] = s;
    __syncthreads();
    if (tid == 0) {
        unsigned cum = 0;
        int c = 255;
        for (; c >= 0; --c) {
            if (cum + part[c] >= (unsigned)KSEL) break;
            cum += part[c];
        }
        if (c < 0) c = 0;
        int bin = 0;
        for (int b = c * 16 + 15; b >= c * 16; --b) {
            if (cum + h[b] >= (unsigned)KSEL) { bin = b; break; }
            cum += h[b];
        }
        thrBin[task] = bin;
    }
}

// ---------- phase 3: compact candidates (block-local LDS buffer, 1 global atomic/block) ----------

__global__ __launch_bounds__(256) void k_compact(const float* __restrict__ o2,
                                                 const float* __restrict__ o3,
                                                 const float* __restrict__ o4,
                                                 const int* __restrict__ thrBin,
                                                 unsigned* __restrict__ cnt,
                                                 unsigned long long* __restrict__ cand) {
    const int task = blockIdx.x, img = task / 3, lvl = task % 3;
    const float* obj = lvl == 0 ? o2 : (lvl == 1 ? o3 : o4);
    const int HW = level_hw(lvl);
    const int total = 3 * HW;
    const float* base = obj + (size_t)img * total;
    const unsigned B = (unsigned)thrBin[task];

    __shared__ unsigned long long buf[CAND_CAP];
    __shared__ unsigned scnt, sbase;
    if (threadIdx.x == 0) scnt = 0u;
    __syncthreads();

    const int per = total / 32;                 // 6144 / 1536 / 384 (div by 4)
    const int per4 = per >> 2;
    const int beg4 = blockIdx.y * per4;
    const float4* base4 = (const float4*)base;
    for (int t = beg4 + threadIdx.x; t < beg4 + per4; t += 256) {
        float4 v = base4[t];
        const int e0 = t * 4;
#pragma unroll
        for (int q = 0; q < 4; ++q) {
            float x = q == 0 ? v.x : (q == 1 ? v.y : (q == 2 ? v.z : v.w));
            unsigned key = fkey(x);
            if ((key >> 20) >= B) {
                unsigned s = atomicAdd(&scnt, 1u);
                if (s < CAND_CAP) {
                    int el = e0 + q;
                    int a = el / HW, pos = el - a * HW;
                    int i = pos * 3 + a;
                    buf[s] = ((unsigned long long)key << 32) | (unsigned)(~(unsigned)i);
                }
            }
        }
    }
    __syncthreads();
    unsigned n = scnt; if (n > CAND_CAP) n = CAND_CAP;
    if (threadIdx.x == 0) sbase = atomicAdd(&cnt[task], n);
    __syncthreads();
    const unsigned b0 = sbase;
    for (unsigned t = threadIdx.x; t < n; t += 256) {
        unsigned slot = b0 + t;
        if (slot < CAND_CAP) cand[task * CAND_CAP + slot] = buf[t];
    }
}

// ---------- phase 4: sort candidates, emit exact top-1000 ----------

__global__ __launch_bounds__(1024) void k_sel(const unsigned* __restrict__ cnt,
                                              const unsigned long long* __restrict__ cand,
                                              int* __restrict__ idx_out) {
    const int task = blockIdx.x, tid = threadIdx.x;
    __shared__ unsigned long long comp[CAND_CAP];
    int n = (int)cnt[task]; if (n > CAND_CAP) n = CAND_CAP;
    for (int t = tid; t < CAND_CAP; t += 1024)
        comp[t] = (t < n) ? cand[task * CAND_CAP + t] : 0ull;
    __syncthreads();

    for (unsigned k = 2; k <= CAND_CAP; k <<= 1) {
        for (unsigned j = k >> 1; j > 0; j >>= 1) {
            for (unsigned i = tid; i < CAND_CAP; i += 1024) {
                unsigned ixj = i ^ j;
                if (ixj > i) {
                    unsigned long long A = comp[i], Bv = comp[ixj];
                    bool desc = ((i & k) == 0);
                    if ((A < Bv) == desc) { comp[i] = Bv; comp[ixj] = A; }
                }
            }
            __syncthreads();
        }
    }

    for (int t = tid; t < KSEL; t += 1024)
        idx_out[task * KSEL + t] = (int)(~(unsigned)(comp[t] & 0xFFFFFFFFull));
}

// ---------- decode + clip + validity + sigmoid (double) ----------

__global__ __launch_bounds__(256) void k_decode(const float* __restrict__ o2, const float* __restrict__ o3, const float* __restrict__ o4,
                                                const float* __restrict__ g2, const float* __restrict__ g3, const float* __restrict__ g4,
                                                const float* __restrict__ a2, const float* __restrict__ a3, const float* __restrict__ a4,
                                                const int* __restrict__ idx,
                                                double* __restrict__ boxes, double* __restrict__ score, int* __restrict__ valid) {
    const int task = blockIdx.x, img = task / 3, lvl = task % 3;
    const float* obj = lvl == 0 ? o2 : (lvl == 1 ? o3 : o4);
    const float* brg = lvl == 0 ? g2 : (lvl == 1 ? g3 : g4);
    const float* anc = lvl == 0 ? a2 : (lvl == 1 ? a3 : a4);
    const int HW = level_hw(lvl);
    const int N = HW * 3;
    const double XC = 4.135166556742356;   // log(1000/16)

    const int r = blockIdx.y * 250 + threadIdx.x;
    if (threadIdx.x < 250 && r < KSEL) {
        int i = idx[task * KSEL + r];
        int a = i % 3, pos = i / 3;
        double x = (double)obj[(size_t)img * 3 * HW + (size_t)a * HW + pos];
        double s = 1.0 / (1.0 + exp(-x));

        const float* bb = brg + (size_t)img * 12 * HW + (size_t)(a * 4) * HW + pos;
        double dx = (double)bb[0];
        double dy = (double)bb[(size_t)HW];
        double dw = (double)bb[(size_t)2 * HW];
        double dh = (double)bb[(size_t)3 * HW];

        const float* an = anc + ((size_t)img * N + (size_t)i) * 4;
        double ax1 = an[0], ay1 = an[1], ax2 = an[2], ay2 = an[3];

        double w = ax2 - ax1 + 1.0, h = ay2 - ay1 + 1.0;
        double cx = ax1 + 0.5 * w, cy = ay1 + 0.5 * h;
        if (dw > XC) dw = XC;
        if (dh > XC) dh = XC;
        double pcx = dx * w + cx, pcy = dy * h + cy;
        double pw = exp(dw) * w, ph = exp(dh) * h;
        double x1 = pcx - 0.5 * pw, y1 = pcy - 0.5 * ph;
        double x2 = pcx + 0.5 * pw - 1.0, y2 = pcy + 0.5 * ph - 1.0;
        x1 = fmin(fmax(x1, 0.0), 1023.0);
        y1 = fmin(fmax(y1, 0.0), 1023.0);
        x2 = fmin(fmax(x2, 0.0), 1023.0);
        y2 = fmin(fmax(y2, 0.0), 1023.0);
        double ws_ = x2 - x1 + 1.0, hs_ = y2 - y1 + 1.0;
        double xc = x1 + ws_ / 2.0, yc = y1 + hs_ / 2.0;
        int v = (ws_ >= 0.0) && (hs_ >= 0.0) && (xc < 1024.0) && (yc < 1024.0);

        double* bo = boxes + (size_t)(task * KSEL + r) * 4;
        bo[0] = x1; bo[1] = y1; bo[2] = x2; bo[3] = y2;
        score[task * KSEL + r] = s;
        valid[task * KSEL + r] = v;
    }
}

// ---------- suppression mask, transposed layout maskT[task][J][i], one wave per 64x64 tile ----------

__global__ __launch_bounds__(512) void k_mask(const double* __restrict__ boxes,
                                              unsigned long long* __restrict__ maskT) {
    const int task = blockIdx.x;
    const int wid = threadIdx.x >> 6, lane = threadIdx.x & 63;
    const int t = blockIdx.y * 8 + wid;          // 17*8 = 136 triangular tiles
    if (t >= 136) return;
    int I = 0, rem = t;
    while (rem >= 16 - I) { rem -= 16 - I; ++I; }
    const int J = I + rem;

    const double* B = boxes + (size_t)task * KSEL * 4;
    const int j = J * 64 + lane;
    const int jc = j < KSEL ? j : KSEL - 1;
    double jx1 = B[jc * 4 + 0], jy1 = B[jc * 4 + 1];
    double jx2 = B[jc * 4 + 2], jy2 = B[jc * 4 + 3];
    double aj = (jx2 - jx1 + 1.0) * (jy2 - jy1 + 1.0);

    unsigned long long* MT = maskT + (size_t)task * 16000 + (size_t)J * KSEL;
    int iend = I * 64 + 64; if (iend > KSEL) iend = KSEL;
    for (int i = I * 64; i < iend; ++i) {
        double ix1 = B[i * 4 + 0], iy1 = B[i * 4 + 1];
        double ix2 = B[i * 4 + 2], iy2 = B[i * 4 + 3];
        double ai = (ix2 - ix1 + 1.0) * (iy2 - iy1 + 1.0);
        double xx1 = fmax(ix1, jx1), yy1 = fmax(iy1, jy1);
        double xx2 = fmin(ix2, jx2), yy2 = fmin(iy2, jy2);
        double iw = xx2 - xx1 + 1.0; iw = iw > 0.0 ? iw : 0.0;
        double ih = yy2 - yy1 + 1.0; ih = ih > 0.0 ? ih : 0.0;
        double inter = iw * ih;
        double iou = inter / (ai + aj - inter);
        bool sup = (j > i) && (j < KSEL) && (iou > 0.7);
        unsigned long long m = __ballot(sup);
        if (lane == 0) MT[i] = m;
    }
}

// ---------- chunked greedy NMS + compaction ----------

__global__ __launch_bounds__(1024) void k_nms(const unsigned long long* __restrict__ maskT,
                                              const int* __restrict__ valid,
                                              const double* __restrict__ score,
                                              int* __restrict__ order, double* __restrict__ s2) {
    const int task = blockIdx.x;
    const int tid = threadIdx.x;
    const int wid = tid >> 6, lane = tid & 63;
    const unsigned long long* MT = maskT + (size_t)task * 16000;

    __shared__ unsigned long long kws[16];
    __shared__ int prefK[16], prefN[16], totKsh;

    if (tid < 16) kws[tid] = 0ull;
    __syncthreads();
    if (tid < KSEL && valid[task * KSEL + tid])
        atomicOr(&kws[tid >> 6], 1ull << (tid & 63));
    __syncthreads();

    // sequential chunks; inside chunk: register shfl chain; then parallel apply
    for (int c = 0; c < 16; ++c) {
        if (wid == 0) {
            const int row = c * 64 + lane;
            unsigned long long m = (row < KSEL) ? MT[(size_t)c * KSEL + row] : 0ull;
            unsigned long long k = kws[c];
#pragma unroll 16
            for (int b = 0; b < 64; ++b) {
                unsigned long long tmp = shfl_u64(m, b);
                if ((k >> b) & 1ull) k &= ~tmp;
            }
            if (lane == 0) kws[c] = k;
        }
        __syncthreads();
        if (wid > c) {
            const int row = c * 64 + lane;           // c <= 14 here, row < 960 < KSEL
            unsigned long long kc = kws[c];
            unsigned long long m = ((kc >> lane) & 1ull) ? MT[(size_t)wid * KSEL + row] : 0ull;
#pragma unroll
            for (int off = 1; off < 64; off <<= 1) m |= shfl_xor_u64(m, off);
            if (lane == 0) kws[wid] &= ~m;
        }
        __syncthreads();
    }

    // prefix sums
    if (tid == 0) {
        int pk = 0, pn = 0;
        for (int l = 0; l < 16; ++l) {
            prefK[l] = pk; prefN[l] = pn;
            int limit = KSEL - 64 * l; if (limit > 64) limit = 64;
            int kb = (int)__popcll(kws[l]);
            pk += kb; pn += limit - kb;
        }
        totKsh = pk;
    }
    __syncthreads();

    // compaction (kept in index order, then suppressed)
    if (tid < 16) {
        unsigned long long kw = kws[tid];
        int limit = KSEL - 64 * tid; if (limit > 64) limit = 64;
        int ck = prefK[tid], cn = totKsh + prefN[tid];
        for (int b = 0; b < limit; ++b) {
            int j = tid * 64 + b;
            if ((kw >> b) & 1ull) {
                order[task * KSEL + ck] = j;
                s2[task * KSEL + ck] = score[task * KSEL + j];
                ++ck;
            } else {
                order[task * KSEL + cn] = j;
                s2[task * KSEL + cn] = NEG_INF_D;
                ++cn;
            }
        }
    }
}

// ---------- per-image 3-way sorted merge (merge-path), final top-1000, level assign ----------

__global__ __launch_bounds__(1024) void k_final(const double* __restrict__ boxes,
                                                const double* __restrict__ s2,
                                                const int* __restrict__ order,
                                                float* __restrict__ out) {
    const int img = blockIdx.x;
    const int tid = threadIdx.x;
    __shared__ unsigned long long Mkey[KSEL];
    __shared__ int Mid[KSEL];                     // 0..1999 = level*1000 + pos

    const double* L0 = s2 + (size_t)(img * 3 + 0) * KSEL;
    const double* L1 = s2 + (size_t)(img * 3 + 1) * KSEL;
    const double* L2 = s2 + (size_t)(img * 3 + 2) * KSEL;

    // ---- phase 1: top-1000 of merge(L0, L1), A(=L0) wins ties ----
    if (tid < KSEL) {
        const int r = tid;
        int lo = 0, hi = r;                       // a in [0, r]
        while (lo < hi) {
            int a = (lo + hi) >> 1;
            if (dkey(L0[a]) >= dkey(L1[r - 1 - a])) lo = a + 1; else hi = a;
        }
        int a = lo, b = r - a;
        unsigned long long ka = dkey(L0[a]), kb = dkey(L1[b]);
        if (ka >= kb) { Mkey[r] = ka; Mid[r] = a; }
        else          { Mkey[r] = kb; Mid[r] = 1000 + b; }
    }
    __syncthreads();

    // ---- phase 2: top-1000 of merge(M, L2), M wins ties ----
    if (tid < KSEL) {
        const int r = tid;
        int lo = 0, hi = r;
        while (lo < hi) {
            int a = (lo + hi) >> 1;
            if (Mkey[a] >= dkey(L2[r - 1 - a])) lo = a + 1; else hi = a;
        }
        int a = lo, b = r - a;
        int e;
        if (a < KSEL && Mkey[a] >= dkey(L2[b])) e = Mid[a];
        else e = 2000 + b;

        int l = e / 1000, rr = e - l * 1000;
        int task = img * 3 + l;
        int pos = order[task * KSEL + rr];
        const double* bo = boxes + (size_t)(task * KSEL + pos) * 4;
        double b0 = bo[0], b1 = bo[1], b2 = bo[2], b3 = bo[3];
        double s = s2[task * KSEL + rr];

        float* fb = out + ((size_t)img * KSEL + r) * 4;
        fb[0] = (float)b0; fb[1] = (float)b1; fb[2] = (float)b2; fb[3] = (float)b3;
        out[8 * KSEL * 4 + img * KSEL + r] = (float)s;

        double area = (b2 - b0 + 1.0) * (b3 - b1 + 1.0);
        double lv = floor(4.0 + log2(sqrt(area) / 224.0 + 1e-6));
        if (!(lv >= 2.0)) lv = 2.0;
        if (lv > 5.0) lv = 5.0;
        out[8 * KSEL * 5 + img * KSEL + r] = (float)lv;
    }
}

// ---------- launch ----------

extern "C" void kernel_launch(void* const* d_in, const int* in_sizes, int n_in,
                              void* d_out, int out_size, void* d_ws, size_t ws_size,
                              hipStream_t stream) {
    const float* o2 = (const float*)d_in[0];
    const float* o3 = (const float*)d_in[1];
    const float* o4 = (const float*)d_in[2];
    const float* g2 = (const float*)d_in[3];
    const float* g3 = (const float*)d_in[4];
    const float* g4 = (const float*)d_in[5];
    const float* a2 = (const float*)d_in[6];
    const float* a3 = (const float*)d_in[7];
    const float* a4 = (const float*)d_in[8];

    char* ws = (char*)d_ws;
    int*                idx   = (int*)(ws + 0);          //  96,000 B
    int*                valid = (int*)(ws + 96000);      //  96,000 B
    double*             score = (double*)(ws + 192000);  // 192,000 B
    double*             boxes = (double*)(ws + 384000);  // 768,000 B
    int*                order = (int*)(ws + 1152000);    //  96,000 B
    double*             s2    = (double*)(ws + 1248000); // 192,000 B
    char*               scr   = ws + 1440000;            // 3,072,000 B shared region

    // top-k scratch (dead after k_sel)
    unsigned*           hist   = (unsigned*)(scr + 0);        // 393,216 B
    unsigned*           cnt    = (unsigned*)(scr + 393216);   //      96 B
    int*                thrBin = (int*)(scr + 393312);        //      96 B
    unsigned long long* cand   = (unsigned long long*)(scr + 393472); // 393,216 B
    // mask region aliases the same space (written by k_mask after k_sel)
    unsigned long long* maskT  = (unsigned long long*)scr;    // 3,072,000 B

    hipMemsetAsync(scr, 0, 393312, stream);   // zero hist + cnt

    k_hist<<<dim3(NTASK, 32), 256, 0, stream>>>(o2, o3, o4, hist);
    k_thresh<<<NTASK, 256, 0, stream>>>(hist, thrBin);
    k_compact<<<dim3(NTASK, 32), 256, 0, stream>>>(o2, o3, o4, thrBin, cnt, cand);
    k_sel<<<NTASK, 1024, 0, stream>>>(cnt, cand, idx);

    k_decode<<<dim3(NTASK, 4), 256, 0, stream>>>(o2, o3, o4, g2, g3, g4, a2, a3, a4,
                                                 idx, boxes, score, valid);
    k_mask<<<dim3(NTASK, 17), 512, 0, stream>>>(boxes, maskT);
    k_nms<<<NTASK, 1024, 0, stream>>>(maskT, valid, score, order, s2);
    k_final<<<NIMG, 1024, 0, stream>>>(boxes, s2, order, (float*)d_out);
}

// Round 7
// 164.831 us; speedup vs baseline: 8.1352x; 1.0353x over previous
//
#include <hip/hip_runtime.h>

#define NTASK 24
#define KSEL 1000
#define NIMG 8
#define NEG_INF_D (-1e30)
#define CAND_CAP 2048

// ---------- helpers ----------

static __device__ __forceinline__ unsigned fkey(float x) {
    unsigned u = __float_as_uint(x);
    return u ^ ((u >> 31) ? 0xFFFFFFFFu : 0x80000000u);
}

static __device__ __forceinline__ unsigned long long dkey(double d) {
    unsigned long long u = (unsigned long long)__double_as_longlong(d);
    if (u >> 63) u = ~u; else u |= 0x8000000000000000ull;
    return u;
}

static __device__ __forceinline__ int level_hw(int lvl) {
    return lvl == 0 ? 65536 : (lvl == 1 ? 16384 : 4096);
}

static __device__ __forceinline__ unsigned long long shfl_xor_u64(unsigned long long v, int m) {
    int lo = __shfl_xor((int)(unsigned)(v & 0xFFFFFFFFull), m, 64);
    int hi = __shfl_xor((int)(unsigned)(v >> 32), m, 64);
    return ((unsigned long long)(unsigned)hi << 32) | (unsigned)lo;
}

// ---------- phase 1: per-task 4096-bin histogram of top-12 key bits ----------

__global__ __launch_bounds__(256) void k_hist(const float* __restrict__ o2,
                                              const float* __restrict__ o3,
                                              const float* __restrict__ o4,
                                              unsigned* __restrict__ hist) {
    const int task = blockIdx.x, img = task / 3, lvl = task % 3;
    const float* obj = lvl == 0 ? o2 : (lvl == 1 ? o3 : o4);
    const int HW = level_hw(lvl);
    const int total = 3 * HW;
    const float* base = obj + (size_t)img * total;
    const int tid = threadIdx.x;

    __shared__ unsigned h[4096];
    for (int t = tid; t < 4096; t += 256) h[t] = 0u;
    __syncthreads();

    const int per = total / 32;
    const int beg = blockIdx.y * per;
    for (int t = beg + tid; t < beg + per; t += 256) {
        unsigned key = fkey(base[t]);
        atomicAdd(&h[key >> 20], 1u);
    }
    __syncthreads();

    unsigned* H = hist + task * 4096;
    for (int t = tid; t < 4096; t += 256)
        if (h[t]) atomicAdd(&H[t], h[t]);
}

// ---------- phase 2: threshold bin ----------

__global__ __launch_bounds__(256) void k_thresh(const unsigned* __restrict__ hist,
                                                int* __restrict__ thrBin) {
    const int task = blockIdx.x, tid = threadIdx.x;
    __shared__ unsigned h[4096];
    __shared__ unsigned part[256];
    const unsigned* H = hist + task * 4096;
    for (int t = tid; t < 4096; t += 256) h[t] = H[t];
    __syncthreads();
    unsigned s = 0;
    for (int q = 0; q < 16; ++q) s += h[tid * 16 + q];
    part[tid] = s;
    __syncthreads();
    if (tid == 0) {
        unsigned cum = 0;
        int c = 255;
        for (; c >= 0; --c) {
            if (cum + part[c] >= (unsigned)KSEL) break;
            cum += part[c];
        }
        if (c < 0) c = 0;
        int bin = 0;
        for (int b = c * 16 + 15; b >= c * 16; --b) {
            if (cum + h[b] >= (unsigned)KSEL) { bin = b; break; }
            cum += h[b];
        }
        thrBin[task] = bin;
    }
}

// ---------- phase 3: compact candidates (block-local LDS buffer, 1 global atomic/block) ----------

__global__ __launch_bounds__(256) void k_compact(const float* __restrict__ o2,
                                                 const float* __restrict__ o3,
                                                 const float* __restrict__ o4,
                                                 const int* __restrict__ thrBin,
                                                 unsigned* __restrict__ cnt,
                                                 unsigned long long* __restrict__ cand) {
    const int task = blockIdx.x, img = task / 3, lvl = task % 3;
    const float* obj = lvl == 0 ? o2 : (lvl == 1 ? o3 : o4);
    const int HW = level_hw(lvl);
    const int total = 3 * HW;
    const float* base = obj + (size_t)img * total;
    const unsigned B = (unsigned)thrBin[task];

    __shared__ unsigned long long buf[CAND_CAP];
    __shared__ unsigned scnt, sbase;
    if (threadIdx.x == 0) scnt = 0u;
    __syncthreads();

    const int per = total / 32;                 // 6144 / 1536 / 384 (div by 4)
    const int per4 = per >> 2;
    const int beg4 = blockIdx.y * per4;
    const float4* base4 = (const float4*)base;
    for (int t = beg4 + threadIdx.x; t < beg4 + per4; t += 256) {
        float4 v = base4[t];
        const int e0 = t * 4;
#pragma unroll
        for (int q = 0; q < 4; ++q) {
            float x = q == 0 ? v.x : (q == 1 ? v.y : (q == 2 ? v.z : v.w));
            unsigned key = fkey(x);
            if ((key >> 20) >= B) {
                unsigned s = atomicAdd(&scnt, 1u);
                if (s < CAND_CAP) {
                    int el = e0 + q;
                    int a = el / HW, pos = el - a * HW;
                    int i = pos * 3 + a;
                    buf[s] = ((unsigned long long)key << 32) | (unsigned)(~(unsigned)i);
                }
            }
        }
    }
    __syncthreads();
    unsigned n = scnt; if (n > CAND_CAP) n = CAND_CAP;
    if (threadIdx.x == 0) sbase = atomicAdd(&cnt[task], n);
    __syncthreads();
    const unsigned b0 = sbase;
    for (unsigned t = threadIdx.x; t < n; t += 256) {
        unsigned slot = b0 + t;
        if (slot < CAND_CAP) cand[task * CAND_CAP + slot] = buf[t];
    }
}

// ---------- phase 4: sort candidates, emit exact top-1000 ----------

__global__ __launch_bounds__(1024) void k_sel(const unsigned* __restrict__ cnt,
                                              const unsigned long long* __restrict__ cand,
                                              int* __restrict__ idx_out) {
    const int task = blockIdx.x, tid = threadIdx.x;
    __shared__ unsigned long long comp[CAND_CAP];
    int n = (int)cnt[task]; if (n > CAND_CAP) n = CAND_CAP;
    for (int t = tid; t < CAND_CAP; t += 1024)
        comp[t] = (t < n) ? cand[task * CAND_CAP + t] : 0ull;
    __syncthreads();

    for (unsigned k = 2; k <= CAND_CAP; k <<= 1) {
        for (unsigned j = k >> 1; j > 0; j >>= 1) {
            for (unsigned i = tid; i < CAND_CAP; i += 1024) {
                unsigned ixj = i ^ j;
                if (ixj > i) {
                    unsigned long long A = comp[i], Bv = comp[ixj];
                    bool desc = ((i & k) == 0);
                    if ((A < Bv) == desc) { comp[i] = Bv; comp[ixj] = A; }
                }
            }
            __syncthreads();
        }
    }

    for (int t = tid; t < KSEL; t += 1024)
        idx_out[task * KSEL + t] = (int)(~(unsigned)(comp[t] & 0xFFFFFFFFull));
}

// ---------- decode + clip + validity + sigmoid (double) ----------

__global__ __launch_bounds__(256) void k_decode(const float* __restrict__ o2, const float* __restrict__ o3, const float* __restrict__ o4,
                                                const float* __restrict__ g2, const float* __restrict__ g3, const float* __restrict__ g4,
                                                const float* __restrict__ a2, const float* __restrict__ a3, const float* __restrict__ a4,
                                                const int* __restrict__ idx,
                                                double* __restrict__ boxes, double* __restrict__ score, int* __restrict__ valid) {
    const int task = blockIdx.x, img = task / 3, lvl = task % 3;
    const float* obj = lvl == 0 ? o2 : (lvl == 1 ? o3 : o4);
    const float* brg = lvl == 0 ? g2 : (lvl == 1 ? g3 : g4);
    const float* anc = lvl == 0 ? a2 : (lvl == 1 ? a3 : a4);
    const int HW = level_hw(lvl);
    const int N = HW * 3;
    const double XC = 4.135166556742356;   // log(1000/16)

    const int r = blockIdx.y * 250 + threadIdx.x;
    if (threadIdx.x < 250 && r < KSEL) {
        int i = idx[task * KSEL + r];
        int a = i % 3, pos = i / 3;
        double x = (double)obj[(size_t)img * 3 * HW + (size_t)a * HW + pos];
        double s = 1.0 / (1.0 + exp(-x));

        const float* bb = brg + (size_t)img * 12 * HW + (size_t)(a * 4) * HW + pos;
        double dx = (double)bb[0];
        double dy = (double)bb[(size_t)HW];
        double dw = (double)bb[(size_t)2 * HW];
        double dh = (double)bb[(size_t)3 * HW];

        const float* an = anc + ((size_t)img * N + (size_t)i) * 4;
        double ax1 = an[0], ay1 = an[1], ax2 = an[2], ay2 = an[3];

        double w = ax2 - ax1 + 1.0, h = ay2 - ay1 + 1.0;
        double cx = ax1 + 0.5 * w, cy = ay1 + 0.5 * h;
        if (dw > XC) dw = XC;
        if (dh > XC) dh = XC;
        double pcx = dx * w + cx, pcy = dy * h + cy;
        double pw = exp(dw) * w, ph = exp(dh) * h;
        double x1 = pcx - 0.5 * pw, y1 = pcy - 0.5 * ph;
        double x2 = pcx + 0.5 * pw - 1.0, y2 = pcy + 0.5 * ph - 1.0;
        x1 = fmin(fmax(x1, 0.0), 1023.0);
        y1 = fmin(fmax(y1, 0.0), 1023.0);
        x2 = fmin(fmax(x2, 0.0), 1023.0);
        y2 = fmin(fmax(y2, 0.0), 1023.0);
        double ws_ = x2 - x1 + 1.0, hs_ = y2 - y1 + 1.0;
        double xc = x1 + ws_ / 2.0, yc = y1 + hs_ / 2.0;
        int v = (ws_ >= 0.0) && (hs_ >= 0.0) && (xc < 1024.0) && (yc < 1024.0);

        double* bo = boxes + (size_t)(task * KSEL + r) * 4;
        bo[0] = x1; bo[1] = y1; bo[2] = x2; bo[3] = y2;
        score[task * KSEL + r] = s;
        valid[task * KSEL + r] = v;
    }
}

// ---------- suppression mask, transposed layout maskT[task][J][i], one wave per 64x64 tile ----------

__global__ __launch_bounds__(512) void k_mask(const double* __restrict__ boxes,
                                              unsigned long long* __restrict__ maskT) {
    const int task = blockIdx.x;
    const int wid = threadIdx.x >> 6, lane = threadIdx.x & 63;
    const int t = blockIdx.y * 8 + wid;          // 17*8 = 136 triangular tiles
    if (t >= 136) return;
    int I = 0, rem = t;
    while (rem >= 16 - I) { rem -= 16 - I; ++I; }
    const int J = I + rem;

    const double* B = boxes + (size_t)task * KSEL * 4;
    const int j = J * 64 + lane;
    const int jc = j < KSEL ? j : KSEL - 1;
    double jx1 = B[jc * 4 + 0], jy1 = B[jc * 4 + 1];
    double jx2 = B[jc * 4 + 2], jy2 = B[jc * 4 + 3];
    double aj = (jx2 - jx1 + 1.0) * (jy2 - jy1 + 1.0);

    unsigned long long* MT = maskT + (size_t)task * 16000 + (size_t)J * KSEL;
    int iend = I * 64 + 64; if (iend > KSEL) iend = KSEL;
    for (int i = I * 64; i < iend; ++i) {
        double ix1 = B[i * 4 + 0], iy1 = B[i * 4 + 1];
        double ix2 = B[i * 4 + 2], iy2 = B[i * 4 + 3];
        double ai = (ix2 - ix1 + 1.0) * (iy2 - iy1 + 1.0);
        double xx1 = fmax(ix1, jx1), yy1 = fmax(iy1, jy1);
        double xx2 = fmin(ix2, jx2), yy2 = fmin(iy2, jy2);
        double iw = xx2 - xx1 + 1.0; iw = iw > 0.0 ? iw : 0.0;
        double ih = yy2 - yy1 + 1.0; ih = ih > 0.0 ? ih : 0.0;
        double inter = iw * ih;
        double iou = inter / (ai + aj - inter);
        bool sup = (j > i) && (j < KSEL) && (iou > 0.7);
        unsigned long long m = __ballot(sup);
        if (lane == 0) MT[i] = m;
    }
}

// ---------- greedy NMS: LDS-resident mask, ffs-driven scalar resolve ----------

__global__ __launch_bounds__(1024) void k_nms(const unsigned long long* __restrict__ maskT,
                                              const int* __restrict__ valid,
                                              const double* __restrict__ score,
                                              int* __restrict__ order, double* __restrict__ s2) {
    const int task = blockIdx.x;
    const int tid = threadIdx.x;
    const int wid = tid >> 6, lane = tid & 63;

    __shared__ unsigned long long Msh[16000];   // 128 KB: Msh[J*1000 + i]
    __shared__ unsigned long long kws[16];
    __shared__ int prefK[16], prefN[16], totKsh;

    // preload whole mask, coalesced 16B
    {
        const ulonglong2* MG = (const ulonglong2*)(maskT + (size_t)task * 16000);
        ulonglong2* ML = (ulonglong2*)Msh;
        for (int t = tid; t < 8000; t += 1024) ML[t] = MG[t];
    }
    if (tid < 16) kws[tid] = 0ull;
    __syncthreads();
    if (tid < KSEL && valid[task * KSEL + tid])
        atomicOr(&kws[tid >> 6], 1ull << (tid & 63));
    __syncthreads();

    for (int c = 0; c < 16; ++c) {
        // resolve chunk c on wave 0: only surviving bits, via readlane
        if (wid == 0) {
            const int row = c * 64 + lane;
            unsigned long long m = (row < KSEL) ? Msh[c * KSEL + row] : 0ull;
            unsigned long long k = kws[c];
            unsigned long long rem = k;
            while (rem) {
                int b = __ffsll((long long)rem) - 1;
                unsigned lo = (unsigned)__builtin_amdgcn_readlane((int)(unsigned)(m & 0xFFFFFFFFull), b);
                unsigned hi = (unsigned)__builtin_amdgcn_readlane((int)(unsigned)(m >> 32), b);
                unsigned long long vict = ((unsigned long long)hi << 32) | lo;
                k &= ~vict;                                   // victims are all > b
                unsigned long long le = (1ull << b) | ((1ull << b) - 1ull);
                rem = k & ~le;                                // surviving bits above b
            }
            if (lane == 0) kws[c] = k;
        }
        __syncthreads();
        // apply chunk c's kept set to later chunks (LDS reads)
        if (wid > c) {
            unsigned long long kc = kws[c];
            unsigned long long m = ((kc >> lane) & 1ull) ? Msh[wid * KSEL + c * 64 + lane] : 0ull;
#pragma unroll
            for (int off = 1; off < 64; off <<= 1) m |= shfl_xor_u64(m, off);
            if (lane == 0) kws[wid] &= ~m;
        }
        __syncthreads();
    }

    // prefix sums
    if (tid == 0) {
        int pk = 0, pn = 0;
        for (int l = 0; l < 16; ++l) {
            prefK[l] = pk; prefN[l] = pn;
            int limit = KSEL - 64 * l; if (limit > 64) limit = 64;
            int kb = (int)__popcll(kws[l]);
            pk += kb; pn += limit - kb;
        }
        totKsh = pk;
    }
    __syncthreads();

    // compaction (kept in index order, then suppressed)
    if (tid < 16) {
        unsigned long long kw = kws[tid];
        int limit = KSEL - 64 * tid; if (limit > 64) limit = 64;
        int ck = prefK[tid], cn = totKsh + prefN[tid];
        for (int b = 0; b < limit; ++b) {
            int j = tid * 64 + b;
            if ((kw >> b) & 1ull) {
                order[task * KSEL + ck] = j;
                s2[task * KSEL + ck] = score[task * KSEL + j];
                ++ck;
            } else {
                order[task * KSEL + cn] = j;
                s2[task * KSEL + cn] = NEG_INF_D;
                ++cn;
            }
        }
    }
}

// ---------- per-image 3-way sorted merge (merge-path), final top-1000, level assign ----------

__global__ __launch_bounds__(1024) void k_final(const double* __restrict__ boxes,
                                                const double* __restrict__ s2,
                                                const int* __restrict__ order,
                                                float* __restrict__ out) {
    const int img = blockIdx.x;
    const int tid = threadIdx.x;
    __shared__ unsigned long long Mkey[KSEL];
    __shared__ int Mid[KSEL];                     // 0..1999 = level*1000 + pos

    const double* L0 = s2 + (size_t)(img * 3 + 0) * KSEL;
    const double* L1 = s2 + (size_t)(img * 3 + 1) * KSEL;
    const double* L2 = s2 + (size_t)(img * 3 + 2) * KSEL;

    // ---- phase 1: top-1000 of merge(L0, L1), A(=L0) wins ties ----
    if (tid < KSEL) {
        const int r = tid;
        int lo = 0, hi = r;                       // a in [0, r]
        while (lo < hi) {
            int a = (lo + hi) >> 1;
            if (dkey(L0[a]) >= dkey(L1[r - 1 - a])) lo = a + 1; else hi = a;
        }
        int a = lo, b = r - a;
        unsigned long long ka = dkey(L0[a]), kb = dkey(L1[b]);
        if (ka >= kb) { Mkey[r] = ka; Mid[r] = a; }
        else          { Mkey[r] = kb; Mid[r] = 1000 + b; }
    }
    __syncthreads();

    // ---- phase 2: top-1000 of merge(M, L2), M wins ties ----
    if (tid < KSEL) {
        const int r = tid;
        int lo = 0, hi = r;
        while (lo < hi) {
            int a = (lo + hi) >> 1;
            if (Mkey[a] >= dkey(L2[r - 1 - a])) lo = a + 1; else hi = a;
        }
        int a = lo, b = r - a;
        int e;
        if (a < KSEL && Mkey[a] >= dkey(L2[b])) e = Mid[a];
        else e = 2000 + b;

        int l = e / 1000, rr = e - l * 1000;
        int task = img * 3 + l;
        int pos = order[task * KSEL + rr];
        const double* bo = boxes + (size_t)(task * KSEL + pos) * 4;
        double b0 = bo[0], b1 = bo[1], b2 = bo[2], b3 = bo[3];
        double s = s2[task * KSEL + rr];

        float* fb = out + ((size_t)img * KSEL + r) * 4;
        fb[0] = (float)b0; fb[1] = (float)b1; fb[2] = (float)b2; fb[3] = (float)b3;
        out[8 * KSEL * 4 + img * KSEL + r] = (float)s;

        double area = (b2 - b0 + 1.0) * (b3 - b1 + 1.0);
        double lv = floor(4.0 + log2(sqrt(area) / 224.0 + 1e-6));
        if (!(lv >= 2.0)) lv = 2.0;
        if (lv > 5.0) lv = 5.0;
        out[8 * KSEL * 5 + img * KSEL + r] = (float)lv;
    }
}

// ---------- launch ----------

extern "C" void kernel_launch(void* const* d_in, const int* in_sizes, int n_in,
                              void* d_out, int out_size, void* d_ws, size_t ws_size,
                              hipStream_t stream) {
    const float* o2 = (const float*)d_in[0];
    const float* o3 = (const float*)d_in[1];
    const float* o4 = (const float*)d_in[2];
    const float* g2 = (const float*)d_in[3];
    const float* g3 = (const float*)d_in[4];
    const float* g4 = (const float*)d_in[5];
    const float* a2 = (const float*)d_in[6];
    const float* a3 = (const float*)d_in[7];
    const float* a4 = (const float*)d_in[8];

    char* ws = (char*)d_ws;
    int*                idx   = (int*)(ws + 0);          //  96,000 B
    int*                valid = (int*)(ws + 96000);      //  96,000 B
    double*             score = (double*)(ws + 192000);  // 192,000 B
    double*             boxes = (double*)(ws + 384000);  // 768,000 B
    int*                order = (int*)(ws + 1152000);    //  96,000 B
    double*             s2    = (double*)(ws + 1248000); // 192,000 B
    char*               scr   = ws + 1440000;            // 3,072,000 B shared region

    // top-k scratch (dead after k_sel)
    unsigned*           hist   = (unsigned*)(scr + 0);        // 393,216 B
    unsigned*           cnt    = (unsigned*)(scr + 393216);   //      96 B
    int*                thrBin = (int*)(scr + 393312);        //      96 B
    unsigned long long* cand   = (unsigned long long*)(scr + 393472); // 393,216 B
    // mask region aliases the same space (written by k_mask after k_sel)
    unsigned long long* maskT  = (unsigned long long*)scr;    // 3,072,000 B

    hipMemsetAsync(scr, 0, 393312, stream);   // zero hist + cnt

    k_hist<<<dim3(NTASK, 32), 256, 0, stream>>>(o2, o3, o4, hist);
    k_thresh<<<NTASK, 256, 0, stream>>>(hist, thrBin);
    k_compact<<<dim3(NTASK, 32), 256, 0, stream>>>(o2, o3, o4, thrBin, cnt, cand);
    k_sel<<<NTASK, 1024, 0, stream>>>(cnt, cand, idx);

    k_decode<<<dim3(NTASK, 4), 256, 0, stream>>>(o2, o3, o4, g2, g3, g4, a2, a3, a4,
                                                 idx, boxes, score, valid);
    k_mask<<<dim3(NTASK, 17), 512, 0, stream>>>(boxes, maskT);
    k_nms<<<NTASK, 1024, 0, stream>>>(maskT, valid, score, order, s2);
    k_final<<<NIMG, 1024, 0, stream>>>(boxes, s2, order, (float*)d_out);
}

// Round 8
// 122.387 us; speedup vs baseline: 10.9565x; 1.3468x over previous
//
#include <hip/hip_runtime.h>

#define NTASK 24
#define KSEL 1000
#define NIMG 8
#define NEG_INF_D (-1e30)
#define CAND_CAP 2048

// ---------- helpers ----------

static __device__ __forceinline__ unsigned fkey(float x) {
    unsigned u = __float_as_uint(x);
    return u ^ ((u >> 31) ? 0xFFFFFFFFu : 0x80000000u);
}

static __device__ __forceinline__ unsigned long long dkey(double d) {
    unsigned long long u = (unsigned long long)__double_as_longlong(d);
    if (u >> 63) u = ~u; else u |= 0x8000000000000000ull;
    return u;
}

static __device__ __forceinline__ int level_hw(int lvl) {
    return lvl == 0 ? 65536 : (lvl == 1 ? 16384 : 4096);
}

// ---------- phase 1: per-task 4096-bin histogram of top-12 key bits ----------

__global__ __launch_bounds__(256) void k_hist(const float* __restrict__ o2,
                                              const float* __restrict__ o3,
                                              const float* __restrict__ o4,
                                              unsigned* __restrict__ hist) {
    const int task = blockIdx.x, img = task / 3, lvl = task % 3;
    const float* obj = lvl == 0 ? o2 : (lvl == 1 ? o3 : o4);
    const int HW = level_hw(lvl);
    const int total = 3 * HW;
    const float* base = obj + (size_t)img * total;
    const int tid = threadIdx.x;

    __shared__ unsigned h[4096];
    for (int t = tid; t < 4096; t += 256) h[t] = 0u;
    __syncthreads();

    const int per = total / 32;
    const int beg = blockIdx.y * per;
    for (int t = beg + tid; t < beg + per; t += 256) {
        unsigned key = fkey(base[t]);
        atomicAdd(&h[key >> 20], 1u);
    }
    __syncthreads();

    unsigned* H = hist + task * 4096;
    for (int t = tid; t < 4096; t += 256)
        if (h[t]) atomicAdd(&H[t], h[t]);
}

// ---------- phase 2: threshold bin ----------

__global__ __launch_bounds__(256) void k_thresh(const unsigned* __restrict__ hist,
                                                int* __restrict__ thrBin) {
    const int task = blockIdx.x, tid = threadIdx.x;
    __shared__ unsigned h[4096];
    __shared__ unsigned part[256];
    const unsigned* H = hist + task * 4096;
    for (int t = tid; t < 4096; t += 256) h[t] = H[t];
    __syncthreads();
    unsigned s = 0;
    for (int q = 0; q < 16; ++q) s += h[tid * 16 + q];
    part[tid] = s;
    __syncthreads();
    if (tid == 0) {
        unsigned cum = 0;
        int c = 255;
        for (; c >= 0; --c) {
            if (cum + part[c] >= (unsigned)KSEL) break;
            cum += part[c];
        }
        if (c < 0) c = 0;
        int bin = 0;
        for (int b = c * 16 + 15; b >= c * 16; --b) {
            if (cum + h[b] >= (unsigned)KSEL) { bin = b; break; }
            cum += h[b];
        }
        thrBin[task] = bin;
    }
}

// ---------- phase 3: compact candidates (block-local LDS buffer, 1 global atomic/block) ----------

__global__ __launch_bounds__(256) void k_compact(const float* __restrict__ o2,
                                                 const float* __restrict__ o3,
                                                 const float* __restrict__ o4,
                                                 const int* __restrict__ thrBin,
                                                 unsigned* __restrict__ cnt,
                                                 unsigned long long* __restrict__ cand) {
    const int task = blockIdx.x, img = task / 3, lvl = task % 3;
    const float* obj = lvl == 0 ? o2 : (lvl == 1 ? o3 : o4);
    const int HW = level_hw(lvl);
    const int total = 3 * HW;
    const float* base = obj + (size_t)img * total;
    const unsigned B = (unsigned)thrBin[task];

    __shared__ unsigned long long buf[CAND_CAP];
    __shared__ unsigned scnt, sbase;
    if (threadIdx.x == 0) scnt = 0u;
    __syncthreads();

    const int per = total / 32;                 // 6144 / 1536 / 384 (div by 4)
    const int per4 = per >> 2;
    const int beg4 = blockIdx.y * per4;
    const float4* base4 = (const float4*)base;
    for (int t = beg4 + threadIdx.x; t < beg4 + per4; t += 256) {
        float4 v = base4[t];
        const int e0 = t * 4;
#pragma unroll
        for (int q = 0; q < 4; ++q) {
            float x = q == 0 ? v.x : (q == 1 ? v.y : (q == 2 ? v.z : v.w));
            unsigned key = fkey(x);
            if ((key >> 20) >= B) {
                unsigned s = atomicAdd(&scnt, 1u);
                if (s < CAND_CAP) {
                    int el = e0 + q;
                    int a = el / HW, pos = el - a * HW;
                    int i = pos * 3 + a;
                    buf[s] = ((unsigned long long)key << 32) | (unsigned)(~(unsigned)i);
                }
            }
        }
    }
    __syncthreads();
    unsigned n = scnt; if (n > CAND_CAP) n = CAND_CAP;
    if (threadIdx.x == 0) sbase = atomicAdd(&cnt[task], n);
    __syncthreads();
    const unsigned b0 = sbase;
    for (unsigned t = threadIdx.x; t < n; t += 256) {
        unsigned slot = b0 + t;
        if (slot < CAND_CAP) cand[task * CAND_CAP + slot] = buf[t];
    }
}

// ---------- phase 4: sort candidates, emit exact top-1000 ----------

__global__ __launch_bounds__(1024) void k_sel(const unsigned* __restrict__ cnt,
                                              const unsigned long long* __restrict__ cand,
                                              int* __restrict__ idx_out) {
    const int task = blockIdx.x, tid = threadIdx.x;
    __shared__ unsigned long long comp[CAND_CAP];
    int n = (int)cnt[task]; if (n > CAND_CAP) n = CAND_CAP;
    for (int t = tid; t < CAND_CAP; t += 1024)
        comp[t] = (t < n) ? cand[task * CAND_CAP + t] : 0ull;
    __syncthreads();

    for (unsigned k = 2; k <= CAND_CAP; k <<= 1) {
        for (unsigned j = k >> 1; j > 0; j >>= 1) {
            for (unsigned i = tid; i < CAND_CAP; i += 1024) {
                unsigned ixj = i ^ j;
                if (ixj > i) {
                    unsigned long long A = comp[i], Bv = comp[ixj];
                    bool desc = ((i & k) == 0);
                    if ((A < Bv) == desc) { comp[i] = Bv; comp[ixj] = A; }
                }
            }
            __syncthreads();
        }
    }

    for (int t = tid; t < KSEL; t += 1024)
        idx_out[task * KSEL + t] = (int)(~(unsigned)(comp[t] & 0xFFFFFFFFull));
}

// ---------- decode + clip + validity + sigmoid (double) ----------

__global__ __launch_bounds__(256) void k_decode(const float* __restrict__ o2, const float* __restrict__ o3, const float* __restrict__ o4,
                                                const float* __restrict__ g2, const float* __restrict__ g3, const float* __restrict__ g4,
                                                const float* __restrict__ a2, const float* __restrict__ a3, const float* __restrict__ a4,
                                                const int* __restrict__ idx,
                                                double* __restrict__ boxes, double* __restrict__ score, int* __restrict__ valid) {
    const int task = blockIdx.x, img = task / 3, lvl = task % 3;
    const float* obj = lvl == 0 ? o2 : (lvl == 1 ? o3 : o4);
    const float* brg = lvl == 0 ? g2 : (lvl == 1 ? g3 : g4);
    const float* anc = lvl == 0 ? a2 : (lvl == 1 ? a3 : a4);
    const int HW = level_hw(lvl);
    const int N = HW * 3;
    const double XC = 4.135166556742356;   // log(1000/16)

    const int r = blockIdx.y * 250 + threadIdx.x;
    if (threadIdx.x < 250 && r < KSEL) {
        int i = idx[task * KSEL + r];
        int a = i % 3, pos = i / 3;
        double x = (double)obj[(size_t)img * 3 * HW + (size_t)a * HW + pos];
        double s = 1.0 / (1.0 + exp(-x));

        const float* bb = brg + (size_t)img * 12 * HW + (size_t)(a * 4) * HW + pos;
        double dx = (double)bb[0];
        double dy = (double)bb[(size_t)HW];
        double dw = (double)bb[(size_t)2 * HW];
        double dh = (double)bb[(size_t)3 * HW];

        const float* an = anc + ((size_t)img * N + (size_t)i) * 4;
        double ax1 = an[0], ay1 = an[1], ax2 = an[2], ay2 = an[3];

        double w = ax2 - ax1 + 1.0, h = ay2 - ay1 + 1.0;
        double cx = ax1 + 0.5 * w, cy = ay1 + 0.5 * h;
        if (dw > XC) dw = XC;
        if (dh > XC) dh = XC;
        double pcx = dx * w + cx, pcy = dy * h + cy;
        double pw = exp(dw) * w, ph = exp(dh) * h;
        double x1 = pcx - 0.5 * pw, y1 = pcy - 0.5 * ph;
        double x2 = pcx + 0.5 * pw - 1.0, y2 = pcy + 0.5 * ph - 1.0;
        x1 = fmin(fmax(x1, 0.0), 1023.0);
        y1 = fmin(fmax(y1, 0.0), 1023.0);
        x2 = fmin(fmax(x2, 0.0), 1023.0);
        y2 = fmin(fmax(y2, 0.0), 1023.0);
        double ws_ = x2 - x1 + 1.0, hs_ = y2 - y1 + 1.0;
        double xc = x1 + ws_ / 2.0, yc = y1 + hs_ / 2.0;
        int v = (ws_ >= 0.0) && (hs_ >= 0.0) && (xc < 1024.0) && (yc < 1024.0);

        double* bo = boxes + (size_t)(task * KSEL + r) * 4;
        bo[0] = x1; bo[1] = y1; bo[2] = x2; bo[3] = y2;
        score[task * KSEL + r] = s;
        valid[task * KSEL + r] = v;
    }
}

// ---------- suppression mask, transposed layout maskT[task][J][i], one wave per 64x64 tile ----------

__global__ __launch_bounds__(512) void k_mask(const double* __restrict__ boxes,
                                              unsigned long long* __restrict__ maskT) {
    const int task = blockIdx.x;
    const int wid = threadIdx.x >> 6, lane = threadIdx.x & 63;
    const int t = blockIdx.y * 8 + wid;          // 17*8 = 136 triangular tiles
    if (t >= 136) return;
    int I = 0, rem = t;
    while (rem >= 16 - I) { rem -= 16 - I; ++I; }
    const int J = I + rem;

    const double* B = boxes + (size_t)task * KSEL * 4;
    const int j = J * 64 + lane;
    const int jc = j < KSEL ? j : KSEL - 1;
    double jx1 = B[jc * 4 + 0], jy1 = B[jc * 4 + 1];
    double jx2 = B[jc * 4 + 2], jy2 = B[jc * 4 + 3];
    double aj = (jx2 - jx1 + 1.0) * (jy2 - jy1 + 1.0);

    unsigned long long* MT = maskT + (size_t)task * 16000 + (size_t)J * KSEL;
    int iend = I * 64 + 64; if (iend > KSEL) iend = KSEL;
    for (int i = I * 64; i < iend; ++i) {
        double ix1 = B[i * 4 + 0], iy1 = B[i * 4 + 1];
        double ix2 = B[i * 4 + 2], iy2 = B[i * 4 + 3];
        double ai = (ix2 - ix1 + 1.0) * (iy2 - iy1 + 1.0);
        double xx1 = fmax(ix1, jx1), yy1 = fmax(iy1, jy1);
        double xx2 = fmin(ix2, jx2), yy2 = fmin(iy2, jy2);
        double iw = xx2 - xx1 + 1.0; iw = iw > 0.0 ? iw : 0.0;
        double ih = yy2 - yy1 + 1.0; ih = ih > 0.0 ? ih : 0.0;
        double inter = iw * ih;
        double iou = inter / (ai + aj - inter);
        bool sup = (j > i) && (j < KSEL) && (iou > 0.7);
        unsigned long long m = __ballot(sup);
        if (lane == 0) MT[i] = m;
    }
}

// ---------- greedy NMS: LDS mask, ballot-skip resolve, sparse atomicAnd apply ----------
// Phase p: waves w>=p apply chunk p-1's kept-set to their own chunk (kws[w] is
// written ONLY by wave w); wave p then resolves chunk p. One barrier per phase.

__global__ __launch_bounds__(1024) void k_nms(const unsigned long long* __restrict__ maskT,
                                              const int* __restrict__ valid,
                                              const double* __restrict__ score,
                                              int* __restrict__ order, double* __restrict__ s2) {
    const int task = blockIdx.x;
    const int tid = threadIdx.x;
    const int wid = tid >> 6, lane = tid & 63;

    __shared__ unsigned long long Msh[16000];   // 128 KB: Msh[J*1000 + i]
    __shared__ unsigned long long kws[16];
    __shared__ int prefK[16], prefN[16], totKsh;

    // preload whole mask, coalesced 16B
    {
        const ulonglong2* MG = (const ulonglong2*)(maskT + (size_t)task * 16000);
        ulonglong2* ML = (ulonglong2*)Msh;
        for (int t = tid; t < 8000; t += 1024) ML[t] = MG[t];
    }
    if (tid < 16) kws[tid] = 0ull;
    __syncthreads();
    if (tid < KSEL && valid[task * KSEL + tid])
        atomicOr(&kws[tid >> 6], 1ull << (tid & 63));
    __syncthreads();

    for (int p = 0; p < 16; ++p) {
        // apply chunk p-1's kept rows to this wave's chunk (sparse)
        if (p > 0 && wid >= p) {
            unsigned long long kp = kws[p - 1];
            unsigned long long m = ((kp >> lane) & 1ull) ? Msh[wid * KSEL + (p - 1) * 64 + lane] : 0ull;
            if (m) atomicAnd(&kws[wid], ~m);
        }
        // resolve chunk p on wave p (only rows that actually suppress something)
        if (wid == p) {
            __threadfence_block();               // own-wave atomics -> visible
            const int row = p * 64 + lane;
            unsigned long long m = (row < KSEL) ? Msh[p * KSEL + row] : 0ull;
            unsigned long long k = kws[p];
            unsigned long long processed = 0ull;
            while (true) {
                unsigned long long sup = __ballot((m & k) != 0ull);
                unsigned long long rem = k & sup & ~processed;
                if (!rem) break;
                int b = __ffsll((long long)rem) - 1;
                unsigned lo = (unsigned)__builtin_amdgcn_readlane((int)(unsigned)(m & 0xFFFFFFFFull), b);
                unsigned hi = (unsigned)__builtin_amdgcn_readlane((int)(unsigned)(m >> 32), b);
                unsigned long long vict = ((unsigned long long)hi << 32) | lo;
                k &= ~vict;                      // victims are all > b
                processed = (1ull << b) | ((1ull << b) - 1ull);
            }
            if (lane == 0) kws[p] = k;
        }
        __syncthreads();
    }

    // prefix sums
    if (tid == 0) {
        int pk = 0, pn = 0;
        for (int l = 0; l < 16; ++l) {
            prefK[l] = pk; prefN[l] = pn;
            int limit = KSEL - 64 * l; if (limit > 64) limit = 64;
            int kb = (int)__popcll(kws[l]);
            pk += kb; pn += limit - kb;
        }
        totKsh = pk;
    }
    __syncthreads();

    // compaction (kept in index order, then suppressed)
    if (tid < 16) {
        unsigned long long kw = kws[tid];
        int limit = KSEL - 64 * tid; if (limit > 64) limit = 64;
        int ck = prefK[tid], cn = totKsh + prefN[tid];
        for (int b = 0; b < limit; ++b) {
            int j = tid * 64 + b;
            if ((kw >> b) & 1ull) {
                order[task * KSEL + ck] = j;
                s2[task * KSEL + ck] = score[task * KSEL + j];
                ++ck;
            } else {
                order[task * KSEL + cn] = j;
                s2[task * KSEL + cn] = NEG_INF_D;
                ++cn;
            }
        }
    }
}

// ---------- per-image 3-way sorted merge (merge-path), final top-1000, level assign ----------

__global__ __launch_bounds__(1024) void k_final(const double* __restrict__ boxes,
                                                const double* __restrict__ s2,
                                                const int* __restrict__ order,
                                                float* __restrict__ out) {
    const int img = blockIdx.x;
    const int tid = threadIdx.x;
    __shared__ unsigned long long Mkey[KSEL];
    __shared__ int Mid[KSEL];                     // 0..1999 = level*1000 + pos

    const double* L0 = s2 + (size_t)(img * 3 + 0) * KSEL;
    const double* L1 = s2 + (size_t)(img * 3 + 1) * KSEL;
    const double* L2 = s2 + (size_t)(img * 3 + 2) * KSEL;

    // ---- phase 1: top-1000 of merge(L0, L1), A(=L0) wins ties ----
    if (tid < KSEL) {
        const int r = tid;
        int lo = 0, hi = r;                       // a in [0, r]
        while (lo < hi) {
            int a = (lo + hi) >> 1;
            if (dkey(L0[a]) >= dkey(L1[r - 1 - a])) lo = a + 1; else hi = a;
        }
        int a = lo, b = r - a;
        unsigned long long ka = dkey(L0[a]), kb = dkey(L1[b]);
        if (ka >= kb) { Mkey[r] = ka; Mid[r] = a; }
        else          { Mkey[r] = kb; Mid[r] = 1000 + b; }
    }
    __syncthreads();

    // ---- phase 2: top-1000 of merge(M, L2), M wins ties ----
    if (tid < KSEL) {
        const int r = tid;
        int lo = 0, hi = r;
        while (lo < hi) {
            int a = (lo + hi) >> 1;
            if (Mkey[a] >= dkey(L2[r - 1 - a])) lo = a + 1; else hi = a;
        }
        int a = lo, b = r - a;
        int e;
        if (a < KSEL && Mkey[a] >= dkey(L2[b])) e = Mid[a];
        else e = 2000 + b;

        int l = e / 1000, rr = e - l * 1000;
        int task = img * 3 + l;
        int pos = order[task * KSEL + rr];
        const double* bo = boxes + (size_t)(task * KSEL + pos) * 4;
        double b0 = bo[0], b1 = bo[1], b2 = bo[2], b3 = bo[3];
        double s = s2[task * KSEL + rr];

        float* fb = out + ((size_t)img * KSEL + r) * 4;
        fb[0] = (float)b0; fb[1] = (float)b1; fb[2] = (float)b2; fb[3] = (float)b3;
        out[8 * KSEL * 4 + img * KSEL + r] = (float)s;

        double area = (b2 - b0 + 1.0) * (b3 - b1 + 1.0);
        double lv = floor(4.0 + log2(sqrt(area) / 224.0 + 1e-6));
        if (!(lv >= 2.0)) lv = 2.0;
        if (lv > 5.0) lv = 5.0;
        out[8 * KSEL * 5 + img * KSEL + r] = (float)lv;
    }
}

// ---------- launch ----------

extern "C" void kernel_launch(void* const* d_in, const int* in_sizes, int n_in,
                              void* d_out, int out_size, void* d_ws, size_t ws_size,
                              hipStream_t stream) {
    const float* o2 = (const float*)d_in[0];
    const float* o3 = (const float*)d_in[1];
    const float* o4 = (const float*)d_in[2];
    const float* g2 = (const float*)d_in[3];
    const float* g3 = (const float*)d_in[4];
    const float* g4 = (const float*)d_in[5];
    const float* a2 = (const float*)d_in[6];
    const float* a3 = (const float*)d_in[7];
    const float* a4 = (const float*)d_in[8];

    char* ws = (char*)d_ws;
    int*                idx   = (int*)(ws + 0);          //  96,000 B
    int*                valid = (int*)(ws + 96000);      //  96,000 B
    double*             score = (double*)(ws + 192000);  // 192,000 B
    double*             boxes = (double*)(ws + 384000);  // 768,000 B
    int*                order = (int*)(ws + 1152000);    //  96,000 B
    double*             s2    = (double*)(ws + 1248000); // 192,000 B
    char*               scr   = ws + 1440000;            // 3,072,000 B shared region

    // top-k scratch (dead after k_sel)
    unsigned*           hist   = (unsigned*)(scr + 0);        // 393,216 B
    unsigned*           cnt    = (unsigned*)(scr + 393216);   //      96 B
    int*                thrBin = (int*)(scr + 393312);        //      96 B
    unsigned long long* cand   = (unsigned long long*)(scr + 393472); // 393,216 B
    // mask region aliases the same space (written by k_mask after k_sel)
    unsigned long long* maskT  = (unsigned long long*)scr;    // 3,072,000 B

    hipMemsetAsync(scr, 0, 393312, stream);   // zero hist + cnt

    k_hist<<<dim3(NTASK, 32), 256, 0, stream>>>(o2, o3, o4, hist);
    k_thresh<<<NTASK, 256, 0, stream>>>(hist, thrBin);
    k_compact<<<dim3(NTASK, 32), 256, 0, stream>>>(o2, o3, o4, thrBin, cnt, cand);
    k_sel<<<NTASK, 1024, 0, stream>>>(cnt, cand, idx);

    k_decode<<<dim3(NTASK, 4), 256, 0, stream>>>(o2, o3, o4, g2, g3, g4, a2, a3, a4,
                                                 idx, boxes, score, valid);
    k_mask<<<dim3(NTASK, 17), 512, 0, stream>>>(boxes, maskT);
    k_nms<<<NTASK, 1024, 0, stream>>>(maskT, valid, score, order, s2);
    k_final<<<NIMG, 1024, 0, stream>>>(boxes, s2, order, (float*)d_out);
}